// Round 1
// baseline (1026.016 us; speedup 1.0000x reference)
//
#include <hip/hip_runtime.h>
#include <math.h>

// DifferentiableKalmanCell: B=4096, STATE=64, OBS=32, coeffs (64,64,11), t scalar.
// One block per batch element; everything staged in LDS; fp32 VALU compute.
// Outputs concat: state_update (B*64) | cov_update (B*64*64) | cov_diag (B*64).

typedef float f4 __attribute__((ext_vector_type(4)));

#define EPSC 1e-7f
static constexpr int SU_OFF = 0;
static constexpr size_t CU_OFF = 4096 * 64;               // 262144
static constexpr size_t CD_OFF = CU_OFF + 4096ull * 4096; // 17039360

__device__ __forceinline__ float dot4(f4 a, f4 b, float acc) {
  acc = fmaf(a[0], b[0], acc);
  acc = fmaf(a[1], b[1], acc);
  acc = fmaf(a[2], b[2], acc);
  acc = fmaf(a[3], b[3], acc);
  return acc;
}

// C[RT][4] += A[r0+i][k] * B[k][c0+j], k = 0..K-1 (NN). stride-68 LDS tiles.
template <int RT, int K>
__device__ __forceinline__ void mm_nn4(float (&acc)[RT][4],
                                       const float (*A)[68], int r0,
                                       const float (*Bm)[68], int c0) {
  for (int kb = 0; kb < K; kb += 4) {
    f4 a[RT], bv[4];
#pragma unroll
    for (int i = 0; i < RT; ++i) a[i] = *(const f4 *)&A[r0 + i][kb];
#pragma unroll
    for (int kk = 0; kk < 4; ++kk) bv[kk] = *(const f4 *)&Bm[kb + kk][c0];
#pragma unroll
    for (int i = 0; i < RT; ++i)
#pragma unroll
      for (int kk = 0; kk < 4; ++kk)
#pragma unroll
        for (int j = 0; j < 4; ++j)
          acc[i][j] = fmaf(a[i][kk], bv[kk][j], acc[i][j]);
  }
}

// C[RT][CT] += A[r0+i][k] * B[c0+j][k], k = 0..K-1 (NT).
template <int RT, int CT, int K>
__device__ __forceinline__ void mm_nt(float (&acc)[RT][CT],
                                      const float (*A)[68], int r0,
                                      const float (*Bm)[68], int c0) {
  for (int kb = 0; kb < K; kb += 4) {
    f4 a[RT], bv[CT];
#pragma unroll
    for (int i = 0; i < RT; ++i) a[i] = *(const f4 *)&A[r0 + i][kb];
#pragma unroll
    for (int j = 0; j < CT; ++j) bv[j] = *(const f4 *)&Bm[c0 + j][kb];
#pragma unroll
    for (int i = 0; i < RT; ++i)
#pragma unroll
      for (int j = 0; j < CT; ++j) acc[i][j] = dot4(a[i], bv[j], acc[i][j]);
  }
}

__global__ __launch_bounds__(256) void kalman_fused(
    const float *__restrict__ obs, const float *__restrict__ prev_state,
    const float *__restrict__ prev_cov, const float *__restrict__ coeffs,
    const float *__restrict__ Hm, const float *__restrict__ logQ,
    const float *__restrict__ logR, const int *__restrict__ tptr,
    float *__restrict__ out) {
  __shared__ __align__(16) float B1[64][68]; // F -> PHt -> I_KH
  __shared__ __align__(16) float B2[64][68]; // P -> cov_pred -> T3 (in-place)
  __shared__ __align__(16) float B3[64][68]; // cheb/dcheb -> T -> T2 -> K|Kr
  __shared__ __align__(16) float sH[32][68];
  __shared__ float sS[32][33];
  __shared__ float sInvD[32];
  __shared__ float sy[64];
  __shared__ float sresid[32];
  __shared__ float sq[64];
  __shared__ float sr[32];
  __shared__ float ypart[4][64];

  const int tid = (int)threadIdx.x;
  const int b = (int)blockIdx.x;
  const int tx = tid & 15, ty = tid >> 4;

  // ---- degree(t): 8 + int(1 + sin(2*pi*t/95)); computed redundantly per thread
  const int tval = tptr[0];
  const double pfrac = (double)tval / 95.0;
  const int D = 9 + (int)(1.0 + sin(6.283185307179586 * pfrac)); // degree+1, 9..11

  // ---- phase 0: stage P, H, q, r; Chebyshev basis + derivative factors
  {
    const float *Pg = prev_cov + (size_t)b * 4096;
    for (int e = tid; e < 1024; e += 256) {
      f4 v = *(const f4 *)(Pg + 4 * e);
      const int r = (4 * e) >> 6, c = (4 * e) & 63;
      *(f4 *)&B2[r][c] = v;
    }
    for (int e = tid; e < 512; e += 256) {
      f4 v = *(const f4 *)(Hm + 4 * e);
      const int r = (4 * e) >> 6, c = (4 * e) & 63;
      *(f4 *)&sH[r][c] = v;
    }
    if (tid < 64) sq[tid] = expf(logQ[tid]);
    else if (tid < 96) sr[tid - 64] = expf(logR[tid - 64]);
  }
  float *B3f = &B3[0][0];
  float (*s_cheb)[12] = (float (*)[12])(B3f);        // 64x12 overlay on B3
  float (*s_dcheb)[12] = (float (*)[12])(B3f + 768); // 64x12 overlay on B3
  if (tid < 64) {
    const float x = prev_state[b * 64 + tid];
    const float tr = tanhf(x);
    const float tv = fminf(fmaxf(tr, -1.0f + EPSC), 1.0f - EPSC);
    const float theta = acosf(tv);
    const float mask = (tr > -1.0f + EPSC && tr < 1.0f - EPSC) ? 1.0f : 0.0f;
    const float dth = -(1.0f - tr * tr) * mask / sqrtf(1.0f - tv * tv);
    for (int d = 0; d < D; ++d) {
      float sv, cv;
      sincosf(theta * (float)d, &sv, &cv);
      s_cheb[tid][d] = cv;
      s_dcheb[tid][d] = -(float)d * sv * dth;
    }
  }
  __syncthreads();

  // ---- phase 1: y (partial) and Jacobian F[o][i] -> B1
  {
    const int o = tid & 63, g = tid >> 6;
    float yacc = 0.f;
    for (int i = g * 16; i < g * 16 + 16; ++i) {
      const float *cp = coeffs + (i * 64 + o) * 11;
      float facc = 0.f;
      for (int d = 0; d < D; ++d) {
        const float cv = cp[d];
        yacc = fmaf(cv, s_cheb[i][d], yacc);
        facc = fmaf(cv, s_dcheb[i][d], facc);
      }
      B1[o][i] = facc;
    }
    ypart[g][o] = yacc;
  }
  __syncthreads();
  if (tid < 64) sy[tid] = ypart[0][tid] + ypart[1][tid] + ypart[2][tid] + ypart[3][tid];
  __syncthreads();

  // ---- residual (threads 0..31, overlapped with phase 2 by the rest)
  if (tid < 32) {
    float racc = obs[b * 32 + tid];
    for (int s = 0; s < 64; s += 4) {
      f4 hv = *(const f4 *)&sH[tid][s];
      racc -= hv[0] * sy[s] + hv[1] * sy[s + 1] + hv[2] * sy[s + 2] + hv[3] * sy[s + 3];
    }
    sresid[tid] = racc;
  }

  // ---- phase 2: T = F * P  (NN, 64x64x64) -> B3 (cheb overlay dead)
  {
    const int r0 = ty * 4, c0 = tx * 4;
    float acc[4][4] = {};
    mm_nn4<4, 64>(acc, B1, r0, B2, c0);
#pragma unroll
    for (int i = 0; i < 4; ++i) {
      f4 v = {acc[i][0], acc[i][1], acc[i][2], acc[i][3]};
      *(f4 *)&B3[r0 + i][c0] = v;
    }
  }
  __syncthreads();

  // ---- phase 3: cov_pred = T * F^T + diag(q) -> B2 (P dead)
  {
    const int r0 = ty * 4, c0 = tx * 4;
    float acc[4][4] = {};
    mm_nt<4, 4, 64>(acc, B3, r0, B1, c0);
#pragma unroll
    for (int i = 0; i < 4; ++i) {
#pragma unroll
      for (int j = 0; j < 4; ++j)
        if (r0 + i == c0 + j) acc[i][j] += sq[r0 + i];
      f4 v = {acc[i][0], acc[i][1], acc[i][2], acc[i][3]};
      *(f4 *)&B2[r0 + i][c0] = v;
    }
  }
  __syncthreads();

  // ---- phase 4: T2 = H * cov_pred (NN, 32x64x64) -> B3 rows 0..31 (T dead)
  {
    const int r0 = ty * 2, c0 = tx * 4;
    float acc[2][4] = {};
    mm_nn4<2, 64>(acc, sH, r0, B2, c0);
#pragma unroll
    for (int i = 0; i < 2; ++i) {
      f4 v = {acc[i][0], acc[i][1], acc[i][2], acc[i][3]};
      *(f4 *)&B3[r0 + i][c0] = v;
    }
  }
  __syncthreads();

  // ---- phase 5: S = T2 * H^T + diag(r) -> sS (32x32x64)
  {
    const int r0 = (tid >> 4) * 2, c0 = (tid & 15) * 2;
    float acc[2][2] = {};
    mm_nt<2, 2, 64>(acc, B3, r0, sH, c0);
#pragma unroll
    for (int i = 0; i < 2; ++i)
#pragma unroll
      for (int j = 0; j < 2; ++j) {
        float v = acc[i][j];
        if (r0 + i == c0 + j) v += sr[r0 + i];
        sS[r0 + i][c0 + j] = v;
      }
  }
  __syncthreads();

  // ---- phase 6: PHt = cov_pred * H^T (64x32x64) -> B1 (F dead)
  {
    const int r0 = ty * 4, c0 = tx * 2;
    float acc[4][2] = {};
    mm_nt<4, 2, 64>(acc, B2, r0, sH, c0);
#pragma unroll
    for (int i = 0; i < 4; ++i) {
      B1[r0 + i][c0] = acc[i][0];
      B1[r0 + i][c0 + 1] = acc[i][1];
    }
  }
  __syncthreads();

  // ---- phase 7: LDL^T factor of S in place (right-looking GE on SPD)
  for (int j = 0; j < 32; ++j) {
    if (tid == 0) sInvD[j] = 1.0f / sS[j][j];
    __syncthreads();
    const float piv = sInvD[j];
#pragma unroll
    for (int ii = 0; ii < 2; ++ii) {
      const int i = j + 1 + ty + 16 * ii;
      if (i <= 31) {
        const float lij = sS[i][j] * piv;
#pragma unroll
        for (int kk = 0; kk < 2; ++kk) {
          const int k = j + 1 + tx + 16 * kk;
          if (k <= 31) sS[i][k] -= lij * sS[k][j];
        }
      }
    }
    __syncthreads();
  }

  // ---- phase 8: 64 simultaneous solves S * K^T = PHt^T (wave 0 only);
  //      write K and K*r into B3; state_update to global.
  if (tid < 64) {
    float w[32];
#pragma unroll
    for (int i = 0; i < 32; ++i) w[i] = B1[tid][i];
    // forward: L z = b (unit diag, M[i][j] = L[i][j]*D[j]); w <- D^-1 L^-1 b
#pragma unroll
    for (int i = 0; i < 32; ++i) {
      float a = w[i];
#pragma unroll
      for (int j = 0; j < i; ++j) a = fmaf(-sS[i][j], w[j], a);
      w[i] = a * sInvD[i];
    }
    // backward: L^T x = w; in place
#pragma unroll
    for (int i = 30; i >= 0; --i) {
      float a = 0.f;
#pragma unroll
      for (int j = i + 1; j < 32; ++j) a = fmaf(sS[j][i], w[j], a);
      w[i] = fmaf(-a, sInvD[i], w[i]);
    }
    // K row tid = w; Kr row = w * r
#pragma unroll
    for (int o = 0; o < 32; o += 4) {
      f4 kv = {w[o], w[o + 1], w[o + 2], w[o + 3]};
      *(f4 *)&B3[tid][o] = kv;
      f4 kr = {w[o] * sr[o], w[o + 1] * sr[o + 1], w[o + 2] * sr[o + 2],
               w[o + 3] * sr[o + 3]};
      *(f4 *)&B3[tid][32 + o] = kr;
    }
    float su = sy[tid];
#pragma unroll
    for (int o = 0; o < 32; ++o) su = fmaf(w[o], sresid[o], su);
    out[SU_OFF + b * 64 + tid] = su;
  }
  __syncthreads();

  // ---- phase 9: I_KH = I - K * H (NN, 64x64x32) -> B1 (PHt dead)
  {
    const int r0 = ty * 4, c0 = tx * 4;
    float acc[4][4] = {};
    mm_nn4<4, 32>(acc, B3, r0, sH, c0);
#pragma unroll
    for (int i = 0; i < 4; ++i) {
      f4 v;
#pragma unroll
      for (int j = 0; j < 4; ++j)
        v[j] = ((r0 + i == c0 + j) ? 1.0f : 0.0f) - acc[i][j];
      *(f4 *)&B1[r0 + i][c0] = v;
    }
  }
  __syncthreads();

  // ---- phase 10: T3 = I_KH * cov_pred, in place into B2, by 32-col blocks
  for (int cb = 0; cb < 2; ++cb) {
    const int c0 = cb * 32 + (tid & 7) * 4;
    const int r0 = (tid >> 3) * 2;
    float acc[2][4] = {};
    mm_nn4<2, 64>(acc, B1, r0, B2, c0);
    __syncthreads(); // all reads of this column block done
#pragma unroll
    for (int i = 0; i < 2; ++i) {
      f4 v = {acc[i][0], acc[i][1], acc[i][2], acc[i][3]};
      *(f4 *)&B2[r0 + i][c0] = v;
    }
  }
  __syncthreads();

  // ---- phase 11: cov_update = T3 * I_KH^T + Kr * K^T ; stores + diag
  {
    const int r0 = ty * 4, c0 = tx * 4;
    float acc[4][4] = {};
    mm_nt<4, 4, 64>(acc, B2, r0, B1, c0); // T3 * I_KH^T
    for (int ob = 0; ob < 32; ob += 4) {  // + Kr * K^T
      f4 a[4], bv[4];
#pragma unroll
      for (int i = 0; i < 4; ++i) a[i] = *(const f4 *)&B3[r0 + i][32 + ob];
#pragma unroll
      for (int j = 0; j < 4; ++j) bv[j] = *(const f4 *)&B3[c0 + j][ob];
#pragma unroll
      for (int i = 0; i < 4; ++i)
#pragma unroll
        for (int j = 0; j < 4; ++j) acc[i][j] = dot4(a[i], bv[j], acc[i][j]);
    }
    float *outc = out + CU_OFF + (size_t)b * 4096;
#pragma unroll
    for (int i = 0; i < 4; ++i) {
      f4 v = {acc[i][0], acc[i][1], acc[i][2], acc[i][3]};
      *(f4 *)&outc[(r0 + i) * 64 + c0] = v;
    }
    if (tx == ty) {
#pragma unroll
      for (int i = 0; i < 4; ++i) out[CD_OFF + b * 64 + r0 + i] = acc[i][i];
    }
  }
}

extern "C" void kernel_launch(void *const *d_in, const int *in_sizes, int n_in,
                              void *d_out, int out_size, void *d_ws,
                              size_t ws_size, hipStream_t stream) {
  const float *obs = (const float *)d_in[0];
  const float *prev_state = (const float *)d_in[1];
  const float *prev_cov = (const float *)d_in[2];
  const float *coeffs = (const float *)d_in[3];
  const float *Hm = (const float *)d_in[4];
  const float *logQ = (const float *)d_in[5];
  const float *logR = (const float *)d_in[6];
  const int *tptr = (const int *)d_in[7];
  (void)in_sizes; (void)n_in; (void)out_size; (void)d_ws; (void)ws_size;
  kalman_fused<<<dim3(4096), dim3(256), 0, stream>>>(
      obs, prev_state, prev_cov, coeffs, Hm, logQ, logR, tptr, (float *)d_out);
}

// Round 3
// 355.922 us; speedup vs baseline: 2.8827x; 2.8827x over previous
//
#include <hip/hip_runtime.h>
#include <math.h>

// DifferentiableKalmanCell: B=4096, STATE=64, OBS=32, coeffs (64,64,11), t scalar.
// One block per batch element; everything staged in LDS; fp32 VALU compute.
// Outputs concat: state_update (B*64) | cov_update (B*64*64) | cov_diag (B*64).
// H (obs_matrix) is 32x64 -- sH MUST be [32][68] (round-2 bug: [32][36] overlapped rows).

typedef float f4 __attribute__((ext_vector_type(4)));

#define EPSC 1e-7f
static constexpr size_t CU_OFF = 4096 * 64;               // 262144
static constexpr size_t CD_OFF = CU_OFF + 4096ull * 4096; // 17039360

__device__ __forceinline__ float dot4(f4 a, f4 b, float acc) {
  acc = fmaf(a[0], b[0], acc);
  acc = fmaf(a[1], b[1], acc);
  acc = fmaf(a[2], b[2], acc);
  acc = fmaf(a[3], b[3], acc);
  return acc;
}

// NN: acc[i][j] += sum_k A[r0+i][k] * B[k][c0+j]  (cols c0..c0+3 contiguous)
template <int RT, int K, int LDA, int LDB>
__device__ __forceinline__ void mm_nn4(float (&acc)[RT][4], const float *A,
                                       int r0, const float *Bm, int c0) {
#pragma unroll 2
  for (int kb = 0; kb < K; kb += 4) {
    f4 a[RT], bv[4];
#pragma unroll
    for (int i = 0; i < RT; ++i) a[i] = *(const f4 *)&A[(r0 + i) * LDA + kb];
#pragma unroll
    for (int kk = 0; kk < 4; ++kk)
      bv[kk] = *(const f4 *)&Bm[(kb + kk) * LDB + c0];
#pragma unroll
    for (int i = 0; i < RT; ++i)
#pragma unroll
      for (int kk = 0; kk < 4; ++kk)
#pragma unroll
        for (int j = 0; j < 4; ++j)
          acc[i][j] = fmaf(a[i][kk], bv[kk][j], acc[i][j]);
  }
}

// NT strided-cols: acc[i][j] += sum_k A[r0+i][k] * B[c0+CS*j][k]
// Lane-column mapping c0 + CS*j keeps B-row reads spread across banks
// (bank = 4*(c0) mod 32, c0 = tx -> 8 bank-groups, 2-way only).
template <int RT, int CT, int K, int CS, int LDA, int LDB>
__device__ __forceinline__ void mm_nt_s(float (&acc)[RT][CT], const float *A,
                                        int r0, const float *Bm, int c0) {
#pragma unroll 2
  for (int kb = 0; kb < K; kb += 4) {
    f4 a[RT], bv[CT];
#pragma unroll
    for (int i = 0; i < RT; ++i) a[i] = *(const f4 *)&A[(r0 + i) * LDA + kb];
#pragma unroll
    for (int j = 0; j < CT; ++j)
      bv[j] = *(const f4 *)&Bm[(c0 + CS * j) * LDB + kb];
#pragma unroll
    for (int i = 0; i < RT; ++i)
#pragma unroll
      for (int j = 0; j < CT; ++j) acc[i][j] = dot4(a[i], bv[j], acc[i][j]);
  }
}

__global__ __launch_bounds__(256, 2) void kalman_fused(
    const float *__restrict__ obs, const float *__restrict__ prev_state,
    const float *__restrict__ prev_cov, const float *__restrict__ coeffs,
    const float *__restrict__ Hm, const float *__restrict__ logQ,
    const float *__restrict__ logR, const int *__restrict__ tptr,
    float *__restrict__ out) {
  __shared__ __align__(16) float B1[64][68]; // F -> PHt -> I_KH
  __shared__ __align__(16) float B2[64][68]; // P -> cov_pred -> T3 (in-place)
  __shared__ __align__(16) float B3[64][68]; // cheb/dcheb -> T -> T2 -> K|Kr
  __shared__ __align__(16) float sH[32][68]; // H is 32x64!
  __shared__ float sS[32][33]; // S -> S^-1 (Gauss-Jordan in place)
  __shared__ float sy[64];
  __shared__ float sresid[32];
  __shared__ float sq[64];
  __shared__ float sr[32];
  __shared__ float ypart[4][64];

  const int tid = (int)threadIdx.x;
  const int b = (int)blockIdx.x;
  const int tx = tid & 15, ty = tid >> 4;

  // ---- degree(t): D = degree+1 = 9 + int(1 + sin(2*pi*t/95))
  const int tval = tptr[0];
  const float ang = 6.28318530717958647f * ((float)tval / 95.0f);
  const int D = 9 + (int)(1.0f + sinf(ang)); // 9..11

  // ---- phase 0: stage P, H, q, r; Chebyshev basis + derivative factors
  {
    const float *Pg = prev_cov + (size_t)b * 4096;
    for (int e = tid; e < 1024; e += 256) {
      f4 v = *(const f4 *)(Pg + 4 * e);
      *(f4 *)&B2[(4 * e) >> 6][(4 * e) & 63] = v;
    }
    for (int e = tid; e < 512; e += 256) {
      f4 v = *(const f4 *)(Hm + 4 * e);
      *(f4 *)&sH[(4 * e) >> 6][(4 * e) & 63] = v;
    }
    if (tid < 64) sq[tid] = expf(logQ[tid]);
    else if (tid < 96) sr[tid - 64] = expf(logR[tid - 64]);
  }
  float *B3f = &B3[0][0];
  float (*s_cheb)[12] = (float (*)[12])(B3f);        // 64x12 overlay on B3
  float (*s_dcheb)[12] = (float (*)[12])(B3f + 768); // 64x12 overlay on B3
  if (tid < 64) {
    const float x = prev_state[b * 64 + tid];
    const float tr = tanhf(x);
    const float tv = fminf(fmaxf(tr, -1.0f + EPSC), 1.0f - EPSC);
    const float theta = acosf(tv);
    const float mask = (tr > -1.0f + EPSC && tr < 1.0f - EPSC) ? 1.0f : 0.0f;
    const float dth = -(1.0f - tr * tr) * mask / sqrtf(1.0f - tv * tv);
    for (int d = 0; d < D; ++d) {
      float sv, cv;
      sincosf(theta * (float)d, &sv, &cv);
      s_cheb[tid][d] = cv;
      s_dcheb[tid][d] = -(float)d * sv * dth;
    }
  }
  __syncthreads();

  // ---- phase 1: y (partial) and Jacobian F[o][i] -> B1
  {
    const int o = tid & 63, g = tid >> 6;
    float yacc = 0.f;
    for (int i = g * 16; i < g * 16 + 16; ++i) {
      const float *cp = coeffs + (i * 64 + o) * 11;
      float facc = 0.f;
      for (int d = 0; d < D; ++d) {
        const float cv = cp[d];
        yacc = fmaf(cv, s_cheb[i][d], yacc);
        facc = fmaf(cv, s_dcheb[i][d], facc);
      }
      B1[o][i] = facc;
    }
    ypart[g][o] = yacc;
  }
  __syncthreads();
  if (tid < 64)
    sy[tid] = ypart[0][tid] + ypart[1][tid] + ypart[2][tid] + ypart[3][tid];
  __syncthreads();

  // ---- residual (threads 0..31; others proceed to phase 2)
  if (tid < 32) {
    float racc = obs[b * 32 + tid];
    for (int s = 0; s < 64; s += 4) {
      f4 hv = *(const f4 *)&sH[tid][s];
      racc -= hv[0] * sy[s] + hv[1] * sy[s + 1] + hv[2] * sy[s + 2] +
              hv[3] * sy[s + 3];
    }
    sresid[tid] = racc;
  }

  // ---- phase 2: T = F * P (NN, 64x64x64) -> B3 (cheb overlay dead)
  {
    const int r0 = ty * 4, c0 = tx * 4;
    float acc[4][4] = {};
    mm_nn4<4, 64, 68, 68>(acc, &B1[0][0], r0, &B2[0][0], c0);
#pragma unroll
    for (int i = 0; i < 4; ++i) {
      f4 v = {acc[i][0], acc[i][1], acc[i][2], acc[i][3]};
      *(f4 *)&B3[r0 + i][c0] = v;
    }
  }
  __syncthreads();

  // ---- phase 3: cov_pred = T * F^T + diag(q) -> B2 (P dead); cols tx+16k
  {
    const int r0 = ty * 4;
    float acc[4][4] = {};
    mm_nt_s<4, 4, 64, 16, 68, 68>(acc, &B3[0][0], r0, &B1[0][0], tx);
#pragma unroll
    for (int i = 0; i < 4; ++i)
#pragma unroll
      for (int k = 0; k < 4; ++k) {
        const int r = r0 + i, c = tx + 16 * k;
        float v = acc[i][k];
        if (r == c) v += sq[r];
        B2[r][c] = v;
      }
  }
  __syncthreads();

  // ---- phase 4: T2 = H * cov_pred (NN, 32x64x64) -> B3 rows 0..31
  {
    const int r0 = ty * 2, c0 = tx * 4;
    float acc[2][4] = {};
    mm_nn4<2, 64, 68, 68>(acc, &sH[0][0], r0, &B2[0][0], c0);
#pragma unroll
    for (int i = 0; i < 2; ++i) {
      f4 v = {acc[i][0], acc[i][1], acc[i][2], acc[i][3]};
      *(f4 *)&B3[r0 + i][c0] = v;
    }
  }
  __syncthreads();

  // ---- phase 5: S = T2 * H^T + diag(r) -> sS; row tid>>3, cols (tid&7)+8k
  {
    const int r = tid >> 3, c0 = tid & 7;
    float acc[1][4] = {};
    mm_nt_s<1, 4, 64, 8, 68, 68>(acc, &B3[0][0], r, &sH[0][0], c0);
#pragma unroll
    for (int k = 0; k < 4; ++k) {
      const int c = c0 + 8 * k;
      float v = acc[0][k];
      if (r == c) v += sr[r];
      sS[r][c] = v;
    }
  }

  // ---- phase 6: PHt = cov_pred * H^T (64x32) -> B1 (F dead); cols tx+16k
  {
    const int r0 = ty * 4;
    float acc[4][2] = {};
    mm_nt_s<4, 2, 64, 16, 68, 68>(acc, &B2[0][0], r0, &sH[0][0], tx);
#pragma unroll
    for (int i = 0; i < 4; ++i) {
      B1[r0 + i][tx] = acc[i][0];
      B1[r0 + i][tx + 16] = acc[i][1];
    }
  }
  __syncthreads();

  // ---- phase 7: S^-1 in place (Gauss-Jordan, no pivoting; S is SPD >= I)
  {
    const int gi = tid >> 3;       // my row 0..31
    const int gk0 = (tid & 7) * 4; // my col base
    for (int p = 0; p < 32; ++p) {
      const float d = 1.0f / sS[p][p];
      const float f = sS[gi][p];
      float rp[4];
#pragma unroll
      for (int k = 0; k < 4; ++k) rp[k] = sS[p][gk0 + k];
      __syncthreads();
      if (gi == p) {
#pragma unroll
        for (int k = 0; k < 4; ++k) {
          const int c = gk0 + k;
          sS[p][c] = (c == p) ? d : rp[k] * d;
        }
      } else {
#pragma unroll
        for (int k = 0; k < 4; ++k) {
          const int c = gk0 + k;
          if (c == p) sS[gi][c] = -f * d;
          else sS[gi][c] = fmaf(-f * d, rp[k], sS[gi][c]);
        }
      }
      __syncthreads();
    }
  }

  // ---- phase 8: K = PHt * S^-1 (64x32x32) -> B3 (K | K*r); state_update
  {
    const int r0 = ty * 4;
    float kacc[4][2] = {};
#pragma unroll 2
    for (int o = 0; o < 32; o += 4) {
      f4 a[4];
#pragma unroll
      for (int i = 0; i < 4; ++i) a[i] = *(const f4 *)&B1[r0 + i][o];
#pragma unroll
      for (int oo = 0; oo < 4; ++oo) {
        const float b0 = sS[o + oo][tx], b1 = sS[o + oo][tx + 16];
#pragma unroll
        for (int i = 0; i < 4; ++i) {
          kacc[i][0] = fmaf(a[i][oo], b0, kacc[i][0]);
          kacc[i][1] = fmaf(a[i][oo], b1, kacc[i][1]);
        }
      }
    }
    const float rv0 = sr[tx], rv1 = sr[tx + 16];
    const float rs0 = sresid[tx], rs1 = sresid[tx + 16];
    float part[4];
#pragma unroll
    for (int i = 0; i < 4; ++i) {
      B3[r0 + i][tx] = kacc[i][0];
      B3[r0 + i][tx + 16] = kacc[i][1];
      B3[r0 + i][32 + tx] = kacc[i][0] * rv0;
      B3[r0 + i][48 + tx] = kacc[i][1] * rv1;
      part[i] = kacc[i][0] * rs0 + kacc[i][1] * rs1;
    }
#pragma unroll
    for (int m = 1; m < 16; m <<= 1)
#pragma unroll
      for (int i = 0; i < 4; ++i) part[i] += __shfl_xor(part[i], m, 64);
    if (tx == 0) {
#pragma unroll
      for (int i = 0; i < 4; ++i) out[b * 64 + r0 + i] = sy[r0 + i] + part[i];
    }
  }
  __syncthreads();

  // ---- phase 9: I_KH = I - K * H (NN, 64x64x32) -> B1 (PHt dead)
  {
    const int r0 = ty * 4, c0 = tx * 4;
    float acc[4][4] = {};
    mm_nn4<4, 32, 68, 68>(acc, &B3[0][0], r0, &sH[0][0], c0);
#pragma unroll
    for (int i = 0; i < 4; ++i) {
      f4 v;
#pragma unroll
      for (int j = 0; j < 4; ++j)
        v[j] = ((r0 + i == c0 + j) ? 1.0f : 0.0f) - acc[i][j];
      *(f4 *)&B1[r0 + i][c0] = v;
    }
  }
  __syncthreads();

  // ---- phase 10: T3 = I_KH * cov_pred, in place into B2, 32-col blocks
  for (int cb = 0; cb < 2; ++cb) {
    const int c0 = cb * 32 + (tid & 7) * 4;
    const int r0 = (tid >> 3) * 2;
    float acc[2][4] = {};
    mm_nn4<2, 64, 68, 68>(acc, &B1[0][0], r0, &B2[0][0], c0);
    __syncthreads(); // all reads of this column block done
#pragma unroll
    for (int i = 0; i < 2; ++i) {
      f4 v = {acc[i][0], acc[i][1], acc[i][2], acc[i][3]};
      *(f4 *)&B2[r0 + i][c0] = v;
    }
  }
  __syncthreads();

  // ---- phase 11: cov_update = T3 * I_KH^T + Kr * K^T ; stores + diag
  {
    const int r0 = ty * 4;
    float acc[4][4] = {};
    mm_nt_s<4, 4, 64, 16, 68, 68>(acc, &B2[0][0], r0, &B1[0][0], tx);
#pragma unroll 2
    for (int ob = 0; ob < 32; ob += 4) { // += Kr * K^T
      f4 a[4], bv[4];
#pragma unroll
      for (int i = 0; i < 4; ++i) a[i] = *(const f4 *)&B3[r0 + i][32 + ob];
#pragma unroll
      for (int k = 0; k < 4; ++k) bv[k] = *(const f4 *)&B3[tx + 16 * k][ob];
#pragma unroll
      for (int i = 0; i < 4; ++i)
#pragma unroll
        for (int k = 0; k < 4; ++k) acc[i][k] = dot4(a[i], bv[k], acc[i][k]);
    }
    float *outc = out + CU_OFF + (size_t)b * 4096;
#pragma unroll
    for (int i = 0; i < 4; ++i)
#pragma unroll
      for (int k = 0; k < 4; ++k) {
        const int r = r0 + i, c = tx + 16 * k;
        outc[r * 64 + c] = acc[i][k];
        if (r == c) out[CD_OFF + b * 64 + r] = acc[i][k];
      }
  }
}

extern "C" void kernel_launch(void *const *d_in, const int *in_sizes, int n_in,
                              void *d_out, int out_size, void *d_ws,
                              size_t ws_size, hipStream_t stream) {
  const float *obs = (const float *)d_in[0];
  const float *prev_state = (const float *)d_in[1];
  const float *prev_cov = (const float *)d_in[2];
  const float *coeffs = (const float *)d_in[3];
  const float *Hm = (const float *)d_in[4];
  const float *logQ = (const float *)d_in[5];
  const float *logR = (const float *)d_in[6];
  const int *tptr = (const int *)d_in[7];
  (void)in_sizes; (void)n_in; (void)out_size; (void)d_ws; (void)ws_size;
  kalman_fused<<<dim3(4096), dim3(256), 0, stream>>>(
      obs, prev_state, prev_cov, coeffs, Hm, logQ, logR, tptr, (float *)d_out);
}

// Round 4
// 258.186 us; speedup vs baseline: 3.9739x; 1.3785x over previous
//
#include <hip/hip_runtime.h>
#include <math.h>

// DifferentiableKalmanCell: B=4096, STATE=64, OBS=32, coeffs (64,64,11), t scalar.
// One block per batch element; everything staged in LDS; fp32 VALU compute.
// Outputs concat: state_update (B*64) | cov_update (B*64*64) | cov_diag (B*64).
//
// R4 algebra: cov_update = cov_pred - K*(H*cov_pred)   (== Joseph form up to
// PHt(S^-1 S - I)K^T ~ 1e-4 absolute, far under threshold), and
// PHt = (H*cov_pred)^T = T2^T, K^T = S^-1 * T2 (S^-1 symmetric).
// Kills 3 of the 6 64-wide GEMM phases. GJ inversion ping-pongs two LDS
// buffers -> 1 barrier/pivot instead of 2.

typedef float f4 __attribute__((ext_vector_type(4)));

#define EPSC 1e-7f
static constexpr size_t CU_OFF = 4096 * 64;               // 262144
static constexpr size_t CD_OFF = CU_OFF + 4096ull * 4096; // 17039360

__device__ __forceinline__ float dot4(f4 a, f4 b, float acc) {
  acc = fmaf(a[0], b[0], acc);
  acc = fmaf(a[1], b[1], acc);
  acc = fmaf(a[2], b[2], acc);
  acc = fmaf(a[3], b[3], acc);
  return acc;
}

// NN: acc[i][j] += sum_k A[r0+i][k] * B[k][c0+j]  (cols c0..c0+3 contiguous)
template <int RT, int K, int LDA, int LDB>
__device__ __forceinline__ void mm_nn4(float (&acc)[RT][4], const float *A,
                                       int r0, const float *Bm, int c0) {
#pragma unroll 2
  for (int kb = 0; kb < K; kb += 4) {
    f4 a[RT], bv[4];
#pragma unroll
    for (int i = 0; i < RT; ++i) a[i] = *(const f4 *)&A[(r0 + i) * LDA + kb];
#pragma unroll
    for (int kk = 0; kk < 4; ++kk)
      bv[kk] = *(const f4 *)&Bm[(kb + kk) * LDB + c0];
#pragma unroll
    for (int i = 0; i < RT; ++i)
#pragma unroll
      for (int kk = 0; kk < 4; ++kk)
#pragma unroll
        for (int j = 0; j < 4; ++j)
          acc[i][j] = fmaf(a[i][kk], bv[kk][j], acc[i][j]);
  }
}

// NT strided-cols: acc[i][j] += sum_k A[r0+i][k] * B[c0+CS*j][k]
template <int RT, int CT, int K, int CS, int LDA, int LDB>
__device__ __forceinline__ void mm_nt_s(float (&acc)[RT][CT], const float *A,
                                        int r0, const float *Bm, int c0) {
#pragma unroll 2
  for (int kb = 0; kb < K; kb += 4) {
    f4 a[RT], bv[CT];
#pragma unroll
    for (int i = 0; i < RT; ++i) a[i] = *(const f4 *)&A[(r0 + i) * LDA + kb];
#pragma unroll
    for (int j = 0; j < CT; ++j)
      bv[j] = *(const f4 *)&Bm[(c0 + CS * j) * LDB + kb];
#pragma unroll
    for (int i = 0; i < RT; ++i)
#pragma unroll
      for (int j = 0; j < CT; ++j) acc[i][j] = dot4(a[i], bv[j], acc[i][j]);
  }
}

__global__ __launch_bounds__(256, 2) void kalman_fused(
    const float *__restrict__ obs, const float *__restrict__ prev_state,
    const float *__restrict__ prev_cov, const float *__restrict__ coeffs,
    const float *__restrict__ Hm, const float *__restrict__ logQ,
    const float *__restrict__ logR, const int *__restrict__ tptr,
    float *__restrict__ out) {
  __shared__ __align__(16) float B1[64][68]; // F (Jacobian)
  __shared__ __align__(16) float B2[64][68]; // P -> cov_pred
  __shared__ __align__(16) float B3[64][68]; // cheb -> T -> T2(r0..31)|Kt(r32..63)
  __shared__ __align__(16) float sH[32][68]; // H is 32x64
  __shared__ __align__(16) float sS[2][32][36]; // S / GJ ping-pong
  __shared__ float sy[64];
  __shared__ float sresid[32];
  __shared__ float sq[64];
  __shared__ float sr[32];
  __shared__ float ypart[4][64];

  const int tid = (int)threadIdx.x;
  const int b = (int)blockIdx.x;
  const int tx = tid & 15, ty = tid >> 4;

  // ---- degree(t): D = degree+1 = 9 + int(1 + sin(2*pi*t/95))
  const int tval = tptr[0];
  const float ang = 6.28318530717958647f * ((float)tval / 95.0f);
  const int D = 9 + (int)(1.0f + sinf(ang)); // 9..11

  // ---- phase 0: stage P, H, q, r; Chebyshev basis + derivative factors
  {
    const float *Pg = prev_cov + (size_t)b * 4096;
    for (int e = tid; e < 1024; e += 256) {
      f4 v = *(const f4 *)(Pg + 4 * e);
      *(f4 *)&B2[(4 * e) >> 6][(4 * e) & 63] = v;
    }
    for (int e = tid; e < 512; e += 256) {
      f4 v = *(const f4 *)(Hm + 4 * e);
      *(f4 *)&sH[(4 * e) >> 6][(4 * e) & 63] = v;
    }
    if (tid < 64) sq[tid] = expf(logQ[tid]);
    else if (tid < 96) sr[tid - 64] = expf(logR[tid - 64]);
  }
  float *B3f = &B3[0][0];
  float (*s_cheb)[12] = (float (*)[12])(B3f);        // 64x12 overlay on B3
  float (*s_dcheb)[12] = (float (*)[12])(B3f + 768); // 64x12 overlay on B3
  if (tid < 64) {
    const float x = prev_state[b * 64 + tid];
    const float tr = tanhf(x);
    const float tv = fminf(fmaxf(tr, -1.0f + EPSC), 1.0f - EPSC);
    const float theta = acosf(tv);
    const float mask = (tr > -1.0f + EPSC && tr < 1.0f - EPSC) ? 1.0f : 0.0f;
    const float dth = -(1.0f - tr * tr) * mask / sqrtf(1.0f - tv * tv);
    for (int d = 0; d < D; ++d) {
      float sv, cv;
      sincosf(theta * (float)d, &sv, &cv);
      s_cheb[tid][d] = cv;
      s_dcheb[tid][d] = -(float)d * sv * dth;
    }
  }
  __syncthreads();

  // ---- phase 1: y (partial) and Jacobian F[o][i] -> B1
  {
    const int o = tid & 63, g = tid >> 6;
    float yacc = 0.f;
    for (int i = g * 16; i < g * 16 + 16; ++i) {
      const float *cp = coeffs + (i * 64 + o) * 11;
      float facc = 0.f;
      for (int d = 0; d < D; ++d) {
        const float cv = cp[d];
        yacc = fmaf(cv, s_cheb[i][d], yacc);
        facc = fmaf(cv, s_dcheb[i][d], facc);
      }
      B1[o][i] = facc;
    }
    ypart[g][o] = yacc;
  }
  __syncthreads();
  if (tid < 64)
    sy[tid] = ypart[0][tid] + ypart[1][tid] + ypart[2][tid] + ypart[3][tid];
  __syncthreads();

  // ---- residual (threads 0..31; others proceed to phase 2)
  if (tid < 32) {
    float racc = obs[b * 32 + tid];
    for (int s = 0; s < 64; s += 4) {
      f4 hv = *(const f4 *)&sH[tid][s];
      racc -= hv[0] * sy[s] + hv[1] * sy[s + 1] + hv[2] * sy[s + 2] +
              hv[3] * sy[s + 3];
    }
    sresid[tid] = racc;
  }

  // ---- phase 2: T = F * P (NN, 64x64x64) -> B3 (cheb overlay dead)
  {
    const int r0 = ty * 4, c0 = tx * 4;
    float acc[4][4] = {};
    mm_nn4<4, 64, 68, 68>(acc, &B1[0][0], r0, &B2[0][0], c0);
#pragma unroll
    for (int i = 0; i < 4; ++i) {
      f4 v = {acc[i][0], acc[i][1], acc[i][2], acc[i][3]};
      *(f4 *)&B3[r0 + i][c0] = v;
    }
  }
  __syncthreads();

  // ---- phase 3: cov_pred = T * F^T + diag(q) -> B2 (P dead); cols tx+16k
  {
    const int r0 = ty * 4;
    float acc[4][4] = {};
    mm_nt_s<4, 4, 64, 16, 68, 68>(acc, &B3[0][0], r0, &B1[0][0], tx);
#pragma unroll
    for (int i = 0; i < 4; ++i)
#pragma unroll
      for (int k = 0; k < 4; ++k) {
        const int r = r0 + i, c = tx + 16 * k;
        float v = acc[i][k];
        if (r == c) v += sq[r];
        B2[r][c] = v;
      }
  }
  __syncthreads();

  // ---- phase 4: T2 = H * cov_pred (32x64x64) -> B3 rows 0..31 (T dead)
  {
    const int r = tid >> 3;       // 0..31
    const int c0 = (tid & 7) * 8; // 0..56
    float acc[8] = {};
#pragma unroll 2
    for (int kb = 0; kb < 64; kb += 4) {
      f4 a = *(const f4 *)&sH[r][kb];
#pragma unroll
      for (int kk = 0; kk < 4; ++kk) {
        f4 b0 = *(const f4 *)&B2[kb + kk][c0];
        f4 b1 = *(const f4 *)&B2[kb + kk][c0 + 4];
#pragma unroll
        for (int j = 0; j < 4; ++j) {
          acc[j] = fmaf(a[kk], b0[j], acc[j]);
          acc[4 + j] = fmaf(a[kk], b1[j], acc[4 + j]);
        }
      }
    }
    f4 w0 = {acc[0], acc[1], acc[2], acc[3]};
    f4 w1 = {acc[4], acc[5], acc[6], acc[7]};
    *(f4 *)&B3[r][c0] = w0;
    *(f4 *)&B3[r][c0 + 4] = w1;
  }
  __syncthreads();

  // ---- phase 5: S = T2 * H^T + diag(r) -> sS[0]
  {
    const int r = tid >> 3, c0i = tid & 7;
    float acc[1][4] = {};
    mm_nt_s<1, 4, 64, 8, 68, 68>(acc, &B3[0][0], r, &sH[0][0], c0i);
#pragma unroll
    for (int k = 0; k < 4; ++k) {
      const int c = c0i + 8 * k;
      float v = acc[0][k];
      if (r == c) v += sr[r];
      sS[0][r][c] = v;
    }
  }
  __syncthreads();

  // ---- phase 6: S^-1 via Gauss-Jordan, ping-pong buffers, 1 barrier/pivot.
  //      No pivoting: S is SPD with S >= I. Result lands back in sS[0].
  {
    const int gi = tid >> 3;       // my row 0..31
    const int gk0 = (tid & 7) * 4; // my col base
    int cur = 0;
    for (int p = 0; p < 32; ++p) {
      const float *S0 = &sS[cur][0][0];
      float *S1 = &sS[cur ^ 1][0][0];
      const float d = 1.0f / S0[p * 36 + p];
      const float fv = S0[gi * 36 + p];
      f4 rp = *(const f4 *)&S0[p * 36 + gk0];
      f4 mine = *(const f4 *)&S0[gi * 36 + gk0];
      f4 nv;
      if (gi == p) {
#pragma unroll
        for (int k = 0; k < 4; ++k)
          nv[k] = (gk0 + k == p) ? d : rp[k] * d;
      } else {
        const float fd = fv * d;
#pragma unroll
        for (int k = 0; k < 4; ++k)
          nv[k] = (gk0 + k == p) ? -fd : fmaf(-fd, rp[k], mine[k]);
      }
      *(f4 *)&S1[gi * 36 + gk0] = nv;
      __syncthreads();
      cur ^= 1;
    } // 32 flips -> result in sS[0]
  }

  // ---- phase 7: K^T = S^-1 * T2 (32x64x32) -> B3 rows 32..63
  //      (PHt == T2^T and S^-1 symmetric => K^T = S^-1 * T2)
  {
    const int o = tid >> 3;       // K^T row 0..31
    const int c0 = (tid & 7) * 8; // state col 0..56
    float acc[8] = {};
#pragma unroll 2
    for (int pb = 0; pb < 32; pb += 4) {
      f4 sv = *(const f4 *)&sS[0][o][pb];
#pragma unroll
      for (int pp = 0; pp < 4; ++pp) {
        f4 t0 = *(const f4 *)&B3[pb + pp][c0];
        f4 t1 = *(const f4 *)&B3[pb + pp][c0 + 4];
#pragma unroll
        for (int j = 0; j < 4; ++j) {
          acc[j] = fmaf(sv[pp], t0[j], acc[j]);
          acc[4 + j] = fmaf(sv[pp], t1[j], acc[4 + j]);
        }
      }
    }
    f4 w0 = {acc[0], acc[1], acc[2], acc[3]};
    f4 w1 = {acc[4], acc[5], acc[6], acc[7]};
    *(f4 *)&B3[32 + o][c0] = w0;
    *(f4 *)&B3[32 + o][c0 + 4] = w1;
  }
  __syncthreads();

  // ---- phase 8: state_update (wave 0) + cov_update = cov_pred - K*T2 (all)
  if (tid < 64) {
    float su = sy[tid];
#pragma unroll 4
    for (int o = 0; o < 32; ++o)
      su = fmaf(B3[32 + o][tid], sresid[o], su);
    out[b * 64 + tid] = su;
  }
  {
    const int r0 = ty * 4, c0 = tx * 4;
    f4 acc[4];
#pragma unroll
    for (int i = 0; i < 4; ++i) acc[i] = *(const f4 *)&B2[r0 + i][c0];
#pragma unroll 4
    for (int o = 0; o < 32; ++o) {
      f4 kv = *(const f4 *)&B3[32 + o][r0]; // K[r0+i][o] = Kt[o][r0+i]
      f4 tv = *(const f4 *)&B3[o][c0];      // T2[o][c0+j]
#pragma unroll
      for (int i = 0; i < 4; ++i)
#pragma unroll
        for (int j = 0; j < 4; ++j) acc[i][j] = fmaf(-kv[i], tv[j], acc[i][j]);
    }
    float *outc = out + CU_OFF + (size_t)b * 4096;
#pragma unroll
    for (int i = 0; i < 4; ++i) {
      *(f4 *)&outc[(r0 + i) * 64 + c0] = acc[i];
      if (tx == ty) out[CD_OFF + b * 64 + r0 + i] = acc[i][i];
    }
  }
}

extern "C" void kernel_launch(void *const *d_in, const int *in_sizes, int n_in,
                              void *d_out, int out_size, void *d_ws,
                              size_t ws_size, hipStream_t stream) {
  const float *obs = (const float *)d_in[0];
  const float *prev_state = (const float *)d_in[1];
  const float *prev_cov = (const float *)d_in[2];
  const float *coeffs = (const float *)d_in[3];
  const float *Hm = (const float *)d_in[4];
  const float *logQ = (const float *)d_in[5];
  const float *logR = (const float *)d_in[6];
  const int *tptr = (const int *)d_in[7];
  (void)in_sizes; (void)n_in; (void)out_size; (void)d_ws; (void)ws_size;
  kalman_fused<<<dim3(4096), dim3(256), 0, stream>>>(
      obs, prev_state, prev_cov, coeffs, Hm, logQ, logR, tptr, (float *)d_out);
}

// Round 5
// 161.906 us; speedup vs baseline: 6.3371x; 1.5947x over previous
//
#include <hip/hip_runtime.h>
#include <math.h>

// DifferentiableKalmanCell: B=4096, STATE=64, OBS=32, coeffs (64,64,11), t scalar.
// One block per batch; MFMA (bf16 split hi/lo, rel err ~5e-5) for all GEMM
// phases; Chebyshev by recurrence; S^-1 by single-wave register Gauss-Jordan.
// Outputs: state_update (B*64) | cov_update (B*64*64) | cov_diag (B*64).

typedef float f4 __attribute__((ext_vector_type(4)));
typedef float f32x4 __attribute__((ext_vector_type(4)));
typedef short b16x8 __attribute__((ext_vector_type(8)));
typedef short b16x4 __attribute__((ext_vector_type(4)));

#define EPSC 1e-7f
#define MFMA(a, b, c) __builtin_amdgcn_mfma_f32_16x16x32_bf16(a, b, c, 0, 0, 0)
static constexpr size_t CU_OFF = 4096 * 64;
static constexpr size_t CD_OFF = CU_OFF + 4096ull * 4096;

__device__ __forceinline__ void split2(float x, short &h, short &l) {
  unsigned u = __float_as_uint(x);
  h = (short)(u >> 16);
  float rem = x - __uint_as_float(u & 0xffff0000u);
  l = (short)(__float_as_uint(rem) >> 16);
}

__device__ __forceinline__ void split8v(f4 a, f4 b, b16x8 &hi, b16x8 &lo) {
#pragma unroll
  for (int j = 0; j < 4; ++j) {
    short hh, ll;
    split2(a[j], hh, ll); hi[j] = hh; lo[j] = ll;
    split2(b[j], hh, ll); hi[4 + j] = hh; lo[4 + j] = ll;
  }
}

__global__ __launch_bounds__(256, 2) void kalman_fused(
    const float *__restrict__ obs, const float *__restrict__ prev_state,
    const float *__restrict__ prev_cov, const float *__restrict__ coeffs,
    const float *__restrict__ Hm, const float *__restrict__ logQ,
    const float *__restrict__ logR, const int *__restrict__ tptr,
    float *__restrict__ out) {
  // LDS pool with phase-based overlays (liveness separated by barriers):
  // @0     sPh u16[64][72] -> p4+: sPHt f32[64][36]
  // @9216  sPl u16[64][72] -> p7+: sK   f32[64][36]
  // @18432 sFh u16[64][72] -> p5+: sS   f32[32][36]
  // @27648 sFl u16[64][72]
  // @36864 sT  f32[64][68]  (ypart[4][64] overlay during p1)
  // @54272 sCov f32[64][68]
  // @71680 misc
  __shared__ __align__(16) unsigned char pool[73216];
  unsigned short *sPh = (unsigned short *)(pool);
  unsigned short *sPl = (unsigned short *)(pool + 9216);
  unsigned short *sFh = (unsigned short *)(pool + 18432);
  unsigned short *sFl = (unsigned short *)(pool + 27648);
  float *sPHt = (float *)(pool);
  float *sK = (float *)(pool + 9216);
  float *sS = (float *)(pool + 18432);
  float *sT = (float *)(pool + 36864);
  float *ypart = (float *)(pool + 36864);
  float *sCov = (float *)(pool + 54272);
  float *sy = (float *)(pool + 71680);
  float *sresid = (float *)(pool + 71936);
  float *sq = (float *)(pool + 72064);
  float *sr = (float *)(pool + 72320);
  float *sTv = (float *)(pool + 72448);
  float *sSn = (float *)(pool + 72704);
  float *sDth = (float *)(pool + 72960);

  const int tid = (int)threadIdx.x;
  const int b = (int)blockIdx.x;
  const int w = tid >> 6;  // wave id 0..3
  const int l = tid & 63;  // lane
  const int lr = l & 15;   // row/col-in-tile
  const int h = l >> 4;    // k-chunk selector 0..3

  // degree(t): D = degree+1 = 9 + int(1 + sin(2*pi*t/95)), D in 9..11
  const int tval = tptr[0];
  const float ang = 6.28318530717958647f * ((float)tval / 95.0f);
  const int D = 9 + (int)(1.0f + sinf(ang));

  // ---- p0: stage P (bf16 hi/lo split), q/r, tanh-chain scalars
  {
    const float *Pg = prev_cov + (size_t)b * 4096;
#pragma unroll
    for (int e = 0; e < 4; ++e) {
      const int idx = tid + 256 * e; // f4 index 0..1023
      f4 v = *(const f4 *)(Pg + 4 * idx);
      const int r = idx >> 4, c = (idx & 15) * 4;
      b16x4 h4, l4;
#pragma unroll
      for (int j = 0; j < 4; ++j) {
        short hh, ll;
        split2(v[j], hh, ll);
        h4[j] = hh; l4[j] = ll;
      }
      *(b16x4 *)(sPh + r * 72 + c) = h4;
      *(b16x4 *)(sPl + r * 72 + c) = l4;
    }
    if (tid < 64) {
      sq[tid] = expf(logQ[tid]);
      const float x = prev_state[b * 64 + tid];
      const float tr_ = tanhf(x);
      const float tv = fminf(fmaxf(tr_, -1.0f + EPSC), 1.0f - EPSC);
      const float sn = sqrtf(fmaxf(1.0f - tv * tv, 0.0f));
      const float mask = (tr_ > -1.0f + EPSC && tr_ < 1.0f - EPSC) ? 1.0f : 0.0f;
      sTv[tid] = tv;
      sSn[tid] = sn;
      sDth[tid] = -(1.0f - tr_ * tr_) * mask / sn;
    } else if (tid < 96) {
      sr[tid - 64] = expf(logR[tid - 64]);
    }
  }
  __syncthreads(); // B0

  // ---- p1: y partials + Jacobian F (Chebyshev recurrence), F -> bf16 split
  {
    const int o = tid & 63, g = tid >> 6;
    float yacc = 0.f;
    float fr[16];
#pragma unroll
    for (int ii = 0; ii < 16; ++ii) {
      const int i = g * 16 + ii;
      const float tv = sTv[i], sn = sSn[i], dth = sDth[i];
      const float *cp = coeffs + (size_t)(i * 64 + o) * 11;
      float cy[11];
#pragma unroll
      for (int d = 0; d < 11; ++d) cy[d] = cp[d]; // scalar loads (4B-aligned)
      if (D < 10) cy[9] = 0.f;
      if (D < 11) cy[10] = 0.f;
      float yac = fmaf(cy[1], tv, cy[0]);
      float wac = cy[1] * sn;
      float cm2 = 1.f, cm1 = tv, sm2 = 0.f, sm1 = sn;
      const float tv2 = 2.f * tv;
#pragma unroll
      for (int d = 2; d <= 10; ++d) {
        const float cc = fmaf(tv2, cm1, -cm2);
        const float ss = fmaf(tv2, sm1, -sm2);
        yac = fmaf(cy[d], cc, yac);
        wac = fmaf(cy[d] * (float)d, ss, wac);
        cm2 = cm1; cm1 = cc; sm2 = sm1; sm1 = ss;
      }
      yacc += yac;
      fr[ii] = -dth * wac;
    }
    b16x8 fh0, fh1, fl0, fl1;
#pragma unroll
    for (int j = 0; j < 8; ++j) {
      short hh, ll;
      split2(fr[j], hh, ll); fh0[j] = hh; fl0[j] = ll;
      split2(fr[8 + j], hh, ll); fh1[j] = hh; fl1[j] = ll;
    }
    *(b16x8 *)(sFh + o * 72 + g * 16) = fh0;
    *(b16x8 *)(sFh + o * 72 + g * 16 + 8) = fh1;
    *(b16x8 *)(sFl + o * 72 + g * 16) = fl0;
    *(b16x8 *)(sFl + o * 72 + g * 16 + 8) = fl1;
    ypart[g * 64 + o] = yacc;
  }
  __syncthreads(); // B1
  if (tid < 64)
    sy[tid] = ypart[tid] + ypart[64 + tid] + ypart[128 + tid] + ypart[192 + tid];
  __syncthreads(); // B2

  // residual (tid<32; overlaps p2 for the rest)
  if (tid < 32) {
    float racc = obs[b * 32 + tid];
    const float *Hr = Hm + tid * 64;
#pragma unroll
    for (int s = 0; s < 64; s += 4) {
      f4 hv = *(const f4 *)(Hr + s);
      racc -= hv[0] * sy[s] + hv[1] * sy[s + 1] + hv[2] * sy[s + 2] +
              hv[3] * sy[s + 3];
    }
    sresid[tid] = racc;
  }

  // ---- p2 (MFMA): T = F * P  (P symmetric -> B-frag = row read)
  {
    f32x4 acc[4] = {{0.f, 0.f, 0.f, 0.f}, {0.f, 0.f, 0.f, 0.f},
                    {0.f, 0.f, 0.f, 0.f}, {0.f, 0.f, 0.f, 0.f}};
    const int m = 16 * w + lr;
#pragma unroll
    for (int kc = 0; kc < 2; ++kc) {
      const int k = kc * 32 + h * 8;
      b16x8 Ah = *(const b16x8 *)(sFh + m * 72 + k);
      b16x8 Al = *(const b16x8 *)(sFl + m * 72 + k);
#pragma unroll
      for (int t = 0; t < 4; ++t) {
        const int n = t * 16 + lr;
        b16x8 Bh = *(const b16x8 *)(sPh + n * 72 + k);
        b16x8 Bl = *(const b16x8 *)(sPl + n * 72 + k);
        acc[t] = MFMA(Ah, Bh, acc[t]);
        acc[t] = MFMA(Al, Bh, acc[t]);
        acc[t] = MFMA(Ah, Bl, acc[t]);
      }
    }
    const int r0 = 16 * w + h * 4;
#pragma unroll
    for (int t = 0; t < 4; ++t)
#pragma unroll
      for (int j = 0; j < 4; ++j)
        sT[(r0 + j) * 68 + t * 16 + lr] = acc[t][j];
  }
  __syncthreads(); // B3

  // ---- p3 (MFMA): cov_pred = T * F^T + diag(q)  (NT: B-frag = F row read)
  {
    f32x4 acc[4] = {{0.f, 0.f, 0.f, 0.f}, {0.f, 0.f, 0.f, 0.f},
                    {0.f, 0.f, 0.f, 0.f}, {0.f, 0.f, 0.f, 0.f}};
    const int m = 16 * w + lr;
#pragma unroll
    for (int kc = 0; kc < 2; ++kc) {
      const int k = kc * 32 + h * 8;
      f4 a0 = *(const f4 *)(sT + m * 68 + k);
      f4 a1 = *(const f4 *)(sT + m * 68 + k + 4);
      b16x8 Ah, Al;
      split8v(a0, a1, Ah, Al);
#pragma unroll
      for (int t = 0; t < 4; ++t) {
        const int n = t * 16 + lr;
        b16x8 Bh = *(const b16x8 *)(sFh + n * 72 + k);
        b16x8 Bl = *(const b16x8 *)(sFl + n * 72 + k);
        acc[t] = MFMA(Ah, Bh, acc[t]);
        acc[t] = MFMA(Al, Bh, acc[t]);
        acc[t] = MFMA(Ah, Bl, acc[t]);
      }
    }
    const int r0 = 16 * w + h * 4;
#pragma unroll
    for (int t = 0; t < 4; ++t)
#pragma unroll
      for (int j = 0; j < 4; ++j) {
        const int rr = r0 + j, cc = t * 16 + lr;
        float v = acc[t][j];
        if (rr == cc) v += sq[rr];
        sCov[rr * 68 + cc] = v;
      }
  }
  __syncthreads(); // B4

  // ---- p4 (MFMA): PHt = cov_pred * H^T  (B-frag = H row from GLOBAL)
  {
    f32x4 acc[2] = {{0.f, 0.f, 0.f, 0.f}, {0.f, 0.f, 0.f, 0.f}};
    const int m = 16 * w + lr;
#pragma unroll
    for (int kc = 0; kc < 2; ++kc) {
      const int k = kc * 32 + h * 8;
      f4 a0 = *(const f4 *)(sCov + m * 68 + k);
      f4 a1 = *(const f4 *)(sCov + m * 68 + k + 4);
      b16x8 Ah, Al;
      split8v(a0, a1, Ah, Al);
#pragma unroll
      for (int t = 0; t < 2; ++t) {
        const int n = t * 16 + lr;
        const float *Hr = Hm + n * 64 + k;
        f4 b0 = *(const f4 *)(Hr);
        f4 b1 = *(const f4 *)(Hr + 4);
        b16x8 Bh, Bl;
        split8v(b0, b1, Bh, Bl);
        acc[t] = MFMA(Ah, Bh, acc[t]);
        acc[t] = MFMA(Al, Bh, acc[t]);
        acc[t] = MFMA(Ah, Bl, acc[t]);
      }
    }
    const int r0 = 16 * w + h * 4;
#pragma unroll
    for (int t = 0; t < 2; ++t)
#pragma unroll
      for (int j = 0; j < 4; ++j)
        sPHt[(r0 + j) * 36 + t * 16 + lr] = acc[t][j];
  }
  __syncthreads(); // B5

  // ---- p5 (MFMA): S = H * PHt + diag(r); wave w -> tile (w>>1, w&1)
  {
    const int tr = w >> 1, tc = w & 1;
    f32x4 acc = {0.f, 0.f, 0.f, 0.f};
    const int m = tr * 16 + lr;
    const int n = tc * 16 + lr;
#pragma unroll
    for (int kc = 0; kc < 2; ++kc) {
      const int k = kc * 32 + h * 8;
      const float *Hr = Hm + m * 64 + k;
      f4 a0 = *(const f4 *)(Hr);
      f4 a1 = *(const f4 *)(Hr + 4);
      b16x8 Ah, Al;
      split8v(a0, a1, Ah, Al);
      f4 b0, b1;
#pragma unroll
      for (int j = 0; j < 4; ++j) b0[j] = sPHt[(k + j) * 36 + n];
#pragma unroll
      for (int j = 0; j < 4; ++j) b1[j] = sPHt[(k + 4 + j) * 36 + n];
      b16x8 Bh, Bl;
      split8v(b0, b1, Bh, Bl);
      acc = MFMA(Ah, Bh, acc);
      acc = MFMA(Al, Bh, acc);
      acc = MFMA(Ah, Bl, acc);
    }
    const int r0 = tr * 16 + h * 4;
#pragma unroll
    for (int j = 0; j < 4; ++j) {
      const int rr = r0 + j, cc = tc * 16 + lr;
      float v = acc[j];
      if (rr == cc) v += sr[rr];
      sS[rr * 36 + cc] = v;
    }
  }
  __syncthreads(); // B6

  // ---- p6: S^-1 in-register Gauss-Jordan on wave 0 (no pivoting, SPD>=I).
  //      lane: row = l>>1, half = l&1 owns 16 cols; pivot row via __shfl.
  if (w == 0) {
    const int mr = l >> 1, half = l & 1;
    float s0[16];
    const float *gbase = sS + mr * 36 + half * 16;
    {
      f4 v0 = *(const f4 *)(gbase + 0), v1 = *(const f4 *)(gbase + 4);
      f4 v2 = *(const f4 *)(gbase + 8), v3 = *(const f4 *)(gbase + 12);
#pragma unroll
      for (int j = 0; j < 4; ++j) {
        s0[j] = v0[j]; s0[4 + j] = v1[j]; s0[8 + j] = v2[j]; s0[12 + j] = v3[j];
      }
    }
#pragma unroll
    for (int p = 0; p < 32; ++p) {
      const int ph = p >> 4, pi = p & 15;
      float prow[16];
#pragma unroll
      for (int j = 0; j < 16; ++j) prow[j] = __shfl(s0[j], 2 * p + half, 64);
      const float dpp = __shfl(s0[pi], 2 * p + ph, 64);
      const float d = 1.0f / dpp;
      const float fv = __shfl(s0[pi], (l & 62) + ph, 64);
      if (mr == p) {
#pragma unroll
        for (int j = 0; j < 16; ++j) s0[j] = prow[j] * d;
        if (half == ph) s0[pi] = d;
      } else {
        const float fd = fv * d;
#pragma unroll
        for (int j = 0; j < 16; ++j) s0[j] = fmaf(-fd, prow[j], s0[j]);
        if (half == ph) s0[pi] = -fd;
      }
    }
    float *wbase = sS + mr * 36 + half * 16;
    f4 w0 = {s0[0], s0[1], s0[2], s0[3]};
    f4 w1 = {s0[4], s0[5], s0[6], s0[7]};
    f4 w2 = {s0[8], s0[9], s0[10], s0[11]};
    f4 w3 = {s0[12], s0[13], s0[14], s0[15]};
    *(f4 *)(wbase + 0) = w0;
    *(f4 *)(wbase + 4) = w1;
    *(f4 *)(wbase + 8) = w2;
    *(f4 *)(wbase + 12) = w3;
  }
  __syncthreads(); // B7

  // ---- p7 (MFMA): K = PHt * S^-1  (S^-1 symmetric -> B-frag = row read)
  {
    f32x4 acc[2] = {{0.f, 0.f, 0.f, 0.f}, {0.f, 0.f, 0.f, 0.f}};
    const int m = 16 * w + lr;
    const int k = h * 8;
    f4 a0 = *(const f4 *)(sPHt + m * 36 + k);
    f4 a1 = *(const f4 *)(sPHt + m * 36 + k + 4);
    b16x8 Ah, Al;
    split8v(a0, a1, Ah, Al);
#pragma unroll
    for (int t = 0; t < 2; ++t) {
      const int n = t * 16 + lr;
      f4 b0 = *(const f4 *)(sS + n * 36 + k);
      f4 b1 = *(const f4 *)(sS + n * 36 + k + 4);
      b16x8 Bh, Bl;
      split8v(b0, b1, Bh, Bl);
      acc[t] = MFMA(Ah, Bh, acc[t]);
      acc[t] = MFMA(Al, Bh, acc[t]);
      acc[t] = MFMA(Ah, Bl, acc[t]);
    }
    const int r0 = 16 * w + h * 4;
#pragma unroll
    for (int t = 0; t < 2; ++t)
#pragma unroll
      for (int j = 0; j < 4; ++j)
        sK[(r0 + j) * 36 + t * 16 + lr] = acc[t][j];
  }
  __syncthreads(); // B8

  // ---- p8: state_update (wave 0) + cov_update = cov_pred - K*PHt^T (MFMA)
  if (tid < 64) {
    float su = sy[tid];
#pragma unroll
    for (int ob = 0; ob < 32; ob += 4) {
      f4 kv = *(const f4 *)(sK + tid * 36 + ob);
      su += kv[0] * sresid[ob] + kv[1] * sresid[ob + 1] +
            kv[2] * sresid[ob + 2] + kv[3] * sresid[ob + 3];
    }
    out[b * 64 + tid] = su;
  }
  {
    const int m = 16 * w + lr;
    const int k = h * 8;
    f4 a0 = *(const f4 *)(sK + m * 36 + k);
    f4 a1 = *(const f4 *)(sK + m * 36 + k + 4);
    a0 = -a0;
    a1 = -a1;
    b16x8 Ah, Al;
    split8v(a0, a1, Ah, Al);
    const int r0 = 16 * w + h * 4;
    float *outc = out + CU_OFF + (size_t)b * 4096;
#pragma unroll
    for (int t = 0; t < 4; ++t) {
      const int n = t * 16 + lr;
      f4 b0 = *(const f4 *)(sPHt + n * 36 + k);
      f4 b1 = *(const f4 *)(sPHt + n * 36 + k + 4);
      b16x8 Bh, Bl;
      split8v(b0, b1, Bh, Bl);
      f32x4 acc;
#pragma unroll
      for (int j = 0; j < 4; ++j) acc[j] = sCov[(r0 + j) * 68 + n];
      acc = MFMA(Ah, Bh, acc);
      acc = MFMA(Al, Bh, acc);
      acc = MFMA(Ah, Bl, acc);
#pragma unroll
      for (int j = 0; j < 4; ++j) {
        const int rr = r0 + j;
        outc[rr * 64 + n] = acc[j];
        if (rr == n) out[CD_OFF + b * 64 + rr] = acc[j];
      }
    }
  }
}

extern "C" void kernel_launch(void *const *d_in, const int *in_sizes, int n_in,
                              void *d_out, int out_size, void *d_ws,
                              size_t ws_size, hipStream_t stream) {
  const float *obs = (const float *)d_in[0];
  const float *prev_state = (const float *)d_in[1];
  const float *prev_cov = (const float *)d_in[2];
  const float *coeffs = (const float *)d_in[3];
  const float *Hm = (const float *)d_in[4];
  const float *logQ = (const float *)d_in[5];
  const float *logR = (const float *)d_in[6];
  const int *tptr = (const int *)d_in[7];
  (void)in_sizes; (void)n_in; (void)out_size; (void)d_ws; (void)ws_size;
  kalman_fused<<<dim3(4096), dim3(256), 0, stream>>>(
      obs, prev_state, prev_cov, coeffs, Hm, logQ, logR, tptr, (float *)d_out);
}

// Round 6
// 128.647 us; speedup vs baseline: 7.9754x; 1.2585x over previous
//
#include <hip/hip_runtime.h>
#include <math.h>

// DifferentiableKalmanCell: B=4096, STATE=64, OBS=32, coeffs (64,64,11), t scalar.
// One block per batch; MFMA (bf16 split hi/lo) for all GEMM phases; Chebyshev by
// recurrence; S^-1 by single-wave register Gauss-Jordan.
// R6: LDS overlay compaction 73216 -> 43008 B => 3 blocks/CU (occupancy push).
//   Region R1 @0     (18432B): P-split(u16) -> T(f32,s68) -> PHt(s36)|K(s36)
//   Region R2 @18432 (18432B): F-split(u16) -> cov_pred(f32,s68)
//   Region R3 @36864 (4608B) : ypart -> S(s36)
//   misc @41472 (1536B)
// Overlay safety: accs held in regs across a barrier before overwriting a
// region another wave read; subsequent reads of the overwritten region are
// wave-band-local (same-wave LDS ops are in-order).

typedef float f4 __attribute__((ext_vector_type(4)));
typedef float f32x4 __attribute__((ext_vector_type(4)));
typedef short b16x8 __attribute__((ext_vector_type(8)));
typedef short b16x4 __attribute__((ext_vector_type(4)));

#define EPSC 1e-7f
#define MFMA(a, b, c) __builtin_amdgcn_mfma_f32_16x16x32_bf16(a, b, c, 0, 0, 0)
static constexpr size_t CU_OFF = 4096 * 64;
static constexpr size_t CD_OFF = CU_OFF + 4096ull * 4096;

__device__ __forceinline__ void split2(float x, short &h, short &l) {
  unsigned u = __float_as_uint(x);
  h = (short)(u >> 16);
  float rem = x - __uint_as_float(u & 0xffff0000u);
  l = (short)(__float_as_uint(rem) >> 16);
}

__device__ __forceinline__ void split8v(f4 a, f4 b, b16x8 &hi, b16x8 &lo) {
#pragma unroll
  for (int j = 0; j < 4; ++j) {
    short hh, ll;
    split2(a[j], hh, ll); hi[j] = hh; lo[j] = ll;
    split2(b[j], hh, ll); hi[4 + j] = hh; lo[4 + j] = ll;
  }
}

__global__ __launch_bounds__(256, 3) void kalman_fused(
    const float *__restrict__ obs, const float *__restrict__ prev_state,
    const float *__restrict__ prev_cov, const float *__restrict__ coeffs,
    const float *__restrict__ Hm, const float *__restrict__ logQ,
    const float *__restrict__ logR, const int *__restrict__ tptr,
    float *__restrict__ out) {
  __shared__ __align__(16) unsigned char pool[43008];
  unsigned short *sPh = (unsigned short *)(pool);          // u16 [64][72]
  unsigned short *sPl = (unsigned short *)(pool + 9216);
  unsigned short *sFh = (unsigned short *)(pool + 18432);
  unsigned short *sFl = (unsigned short *)(pool + 27648);
  float *sT = (float *)(pool);            // f32 [64][68] over P
  float *sCov = (float *)(pool + 18432);  // f32 [64][68] over F
  float *sPHt = (float *)(pool);          // f32 [64][36] over T(lo)
  float *sK = (float *)(pool + 9216);     // f32 [64][36] over T(hi)
  float *sS = (float *)(pool + 36864);    // f32 [32][36]
  float *ypart = (float *)(pool + 36864); // 4x64 over S (dead before p5)
  float *sy = (float *)(pool + 41472);
  float *sresid = (float *)(pool + 41728);
  float *sq = (float *)(pool + 41856);
  float *sr = (float *)(pool + 42112);
  float *sTv = (float *)(pool + 42240);
  float *sSn = (float *)(pool + 42496);
  float *sDth = (float *)(pool + 42752);

  const int tid = (int)threadIdx.x;
  const int b = (int)blockIdx.x;
  const int w = tid >> 6;  // wave id 0..3
  const int l = tid & 63;  // lane
  const int lr = l & 15;   // row/col-in-tile
  const int h = l >> 4;    // k-chunk selector 0..3

  // degree(t): D = degree+1 = 9 + int(1 + sin(2*pi*t/95)), D in 9..11
  const int tval = tptr[0];
  const float ang = 6.28318530717958647f * ((float)tval / 95.0f);
  const int D = 9 + (int)(1.0f + sinf(ang));

  // ---- p0: stage P (bf16 hi/lo split), q/r, tanh-chain scalars
  {
    const float *Pg = prev_cov + (size_t)b * 4096;
#pragma unroll
    for (int e = 0; e < 4; ++e) {
      const int idx = tid + 256 * e; // f4 index 0..1023
      f4 v = *(const f4 *)(Pg + 4 * idx);
      const int r = idx >> 4, c = (idx & 15) * 4;
      b16x4 h4, l4;
#pragma unroll
      for (int j = 0; j < 4; ++j) {
        short hh, ll;
        split2(v[j], hh, ll);
        h4[j] = hh; l4[j] = ll;
      }
      *(b16x4 *)(sPh + r * 72 + c) = h4;
      *(b16x4 *)(sPl + r * 72 + c) = l4;
    }
    if (tid < 64) {
      sq[tid] = expf(logQ[tid]);
      const float x = prev_state[b * 64 + tid];
      const float tr_ = tanhf(x);
      const float tv = fminf(fmaxf(tr_, -1.0f + EPSC), 1.0f - EPSC);
      const float sn = sqrtf(fmaxf(1.0f - tv * tv, 0.0f));
      const float mask = (tr_ > -1.0f + EPSC && tr_ < 1.0f - EPSC) ? 1.0f : 0.0f;
      sTv[tid] = tv;
      sSn[tid] = sn;
      sDth[tid] = -(1.0f - tr_ * tr_) * mask / sn;
    } else if (tid < 96) {
      sr[tid - 64] = expf(logR[tid - 64]);
    }
  }
  __syncthreads(); // B0

  // ---- p1: y partials + Jacobian F (Chebyshev recurrence), F -> bf16 split
  {
    const int o = tid & 63, g = tid >> 6;
    float yacc = 0.f;
    float fr[16];
#pragma unroll
    for (int ii = 0; ii < 16; ++ii) {
      const int i = g * 16 + ii;
      const float tv = sTv[i], sn = sSn[i], dth = sDth[i];
      const float *cp = coeffs + (size_t)(i * 64 + o) * 11;
      float cy[11];
#pragma unroll
      for (int d = 0; d < 11; ++d) cy[d] = cp[d];
      if (D < 10) cy[9] = 0.f;
      if (D < 11) cy[10] = 0.f;
      float yac = fmaf(cy[1], tv, cy[0]);
      float wac = cy[1] * sn;
      float cm2 = 1.f, cm1 = tv, sm2 = 0.f, sm1 = sn;
      const float tv2 = 2.f * tv;
#pragma unroll
      for (int d = 2; d <= 10; ++d) {
        const float cc = fmaf(tv2, cm1, -cm2);
        const float ss = fmaf(tv2, sm1, -sm2);
        yac = fmaf(cy[d], cc, yac);
        wac = fmaf(cy[d] * (float)d, ss, wac);
        cm2 = cm1; cm1 = cc; sm2 = sm1; sm1 = ss;
      }
      yacc += yac;
      fr[ii] = -dth * wac;
    }
    b16x8 fh0, fh1, fl0, fl1;
#pragma unroll
    for (int j = 0; j < 8; ++j) {
      short hh, ll;
      split2(fr[j], hh, ll); fh0[j] = hh; fl0[j] = ll;
      split2(fr[8 + j], hh, ll); fh1[j] = hh; fl1[j] = ll;
    }
    *(b16x8 *)(sFh + o * 72 + g * 16) = fh0;
    *(b16x8 *)(sFh + o * 72 + g * 16 + 8) = fh1;
    *(b16x8 *)(sFl + o * 72 + g * 16) = fl0;
    *(b16x8 *)(sFl + o * 72 + g * 16 + 8) = fl1;
    ypart[g * 64 + o] = yacc;
  }
  __syncthreads(); // B1
  if (tid < 64)
    sy[tid] = ypart[tid] + ypart[64 + tid] + ypart[128 + tid] + ypart[192 + tid];
  __syncthreads(); // B2

  // residual (tid<32; overlaps p2 for the rest)
  if (tid < 32) {
    float racc = obs[b * 32 + tid];
    const float *Hr = Hm + tid * 64;
#pragma unroll
    for (int s = 0; s < 64; s += 4) {
      f4 hv = *(const f4 *)(Hr + s);
      racc -= hv[0] * sy[s] + hv[1] * sy[s + 1] + hv[2] * sy[s + 2] +
              hv[3] * sy[s + 3];
    }
    sresid[tid] = racc;
  }

  // ---- p2 (MFMA): T = F * P (P symmetric -> B-frag = row read). Accs stay
  //      in regs across B3, then T overwrites the P region (band-local use).
  f32x4 accT[4] = {{0.f, 0.f, 0.f, 0.f}, {0.f, 0.f, 0.f, 0.f},
                   {0.f, 0.f, 0.f, 0.f}, {0.f, 0.f, 0.f, 0.f}};
  {
    const int m = 16 * w + lr;
#pragma unroll
    for (int kc = 0; kc < 2; ++kc) {
      const int k = kc * 32 + h * 8;
      b16x8 Ah = *(const b16x8 *)(sFh + m * 72 + k);
      b16x8 Al = *(const b16x8 *)(sFl + m * 72 + k);
#pragma unroll
      for (int t = 0; t < 4; ++t) {
        const int n = t * 16 + lr;
        b16x8 Bh = *(const b16x8 *)(sPh + n * 72 + k);
        b16x8 Bl = *(const b16x8 *)(sPl + n * 72 + k);
        accT[t] = MFMA(Ah, Bh, accT[t]);
        accT[t] = MFMA(Al, Bh, accT[t]);
        accT[t] = MFMA(Ah, Bl, accT[t]);
      }
    }
  }
  __syncthreads(); // B3: all P reads drained; safe to overwrite R1 with T
  {
    const int r0 = 16 * w + h * 4;
#pragma unroll
    for (int t = 0; t < 4; ++t)
#pragma unroll
      for (int j = 0; j < 4; ++j)
        sT[(r0 + j) * 68 + t * 16 + lr] = accT[t][j];
  }

  // ---- p3 (MFMA): cov_pred = T * F^T + diag(q). A = T band-local (own wave
  //      wrote it; same-wave LDS is in-order). Accs in regs across B4, then
  //      cov_pred overwrites the F region.
  f32x4 accC[4] = {{0.f, 0.f, 0.f, 0.f}, {0.f, 0.f, 0.f, 0.f},
                   {0.f, 0.f, 0.f, 0.f}, {0.f, 0.f, 0.f, 0.f}};
  {
    const int m = 16 * w + lr;
#pragma unroll
    for (int kc = 0; kc < 2; ++kc) {
      const int k = kc * 32 + h * 8;
      f4 a0 = *(const f4 *)(sT + m * 68 + k);
      f4 a1 = *(const f4 *)(sT + m * 68 + k + 4);
      b16x8 Ah, Al;
      split8v(a0, a1, Ah, Al);
#pragma unroll
      for (int t = 0; t < 4; ++t) {
        const int n = t * 16 + lr;
        b16x8 Bh = *(const b16x8 *)(sFh + n * 72 + k);
        b16x8 Bl = *(const b16x8 *)(sFl + n * 72 + k);
        accC[t] = MFMA(Ah, Bh, accC[t]);
        accC[t] = MFMA(Al, Bh, accC[t]);
        accC[t] = MFMA(Ah, Bl, accC[t]);
      }
    }
  }
  __syncthreads(); // B4: all F and T reads drained; overwrite R2 with cov_pred
  {
    const int r0 = 16 * w + h * 4;
#pragma unroll
    for (int t = 0; t < 4; ++t)
#pragma unroll
      for (int j = 0; j < 4; ++j) {
        const int rr = r0 + j, cc = t * 16 + lr;
        float v = accC[t][j];
        if (rr == cc) v += sq[rr];
        sCov[rr * 68 + cc] = v;
      }
  }

  // ---- p4 (MFMA): PHt = cov_pred * H^T (A = cov band-local; B = H global).
  //      Writes sPHt over dead T rows 0..31 (T reads all pre-B4).
  {
    f32x4 acc[2] = {{0.f, 0.f, 0.f, 0.f}, {0.f, 0.f, 0.f, 0.f}};
    const int m = 16 * w + lr;
#pragma unroll
    for (int kc = 0; kc < 2; ++kc) {
      const int k = kc * 32 + h * 8;
      f4 a0 = *(const f4 *)(sCov + m * 68 + k);
      f4 a1 = *(const f4 *)(sCov + m * 68 + k + 4);
      b16x8 Ah, Al;
      split8v(a0, a1, Ah, Al);
#pragma unroll
      for (int t = 0; t < 2; ++t) {
        const int n = t * 16 + lr;
        const float *Hr = Hm + n * 64 + k;
        f4 b0 = *(const f4 *)(Hr);
        f4 b1 = *(const f4 *)(Hr + 4);
        b16x8 Bh, Bl;
        split8v(b0, b1, Bh, Bl);
        acc[t] = MFMA(Ah, Bh, acc[t]);
        acc[t] = MFMA(Al, Bh, acc[t]);
        acc[t] = MFMA(Ah, Bl, acc[t]);
      }
    }
    const int r0 = 16 * w + h * 4;
#pragma unroll
    for (int t = 0; t < 2; ++t)
#pragma unroll
      for (int j = 0; j < 4; ++j)
        sPHt[(r0 + j) * 36 + t * 16 + lr] = acc[t][j];
  }
  __syncthreads(); // B5: sPHt complete (p5 gathers cross-wave)

  // ---- p5 (MFMA): S = H * PHt + diag(r); wave w -> tile (w>>1, w&1)
  {
    const int tr = w >> 1, tc = w & 1;
    f32x4 acc = {0.f, 0.f, 0.f, 0.f};
    const int m = tr * 16 + lr;
    const int n = tc * 16 + lr;
#pragma unroll
    for (int kc = 0; kc < 2; ++kc) {
      const int k = kc * 32 + h * 8;
      const float *Hr = Hm + m * 64 + k;
      f4 a0 = *(const f4 *)(Hr);
      f4 a1 = *(const f4 *)(Hr + 4);
      b16x8 Ah, Al;
      split8v(a0, a1, Ah, Al);
      f4 b0, b1;
#pragma unroll
      for (int j = 0; j < 4; ++j) b0[j] = sPHt[(k + j) * 36 + n];
#pragma unroll
      for (int j = 0; j < 4; ++j) b1[j] = sPHt[(k + 4 + j) * 36 + n];
      b16x8 Bh, Bl;
      split8v(b0, b1, Bh, Bl);
      acc = MFMA(Ah, Bh, acc);
      acc = MFMA(Al, Bh, acc);
      acc = MFMA(Ah, Bl, acc);
    }
    const int r0 = tr * 16 + h * 4;
#pragma unroll
    for (int j = 0; j < 4; ++j) {
      const int rr = r0 + j, cc = tc * 16 + lr;
      float v = acc[j];
      if (rr == cc) v += sr[rr];
      sS[rr * 36 + cc] = v;
    }
  }
  __syncthreads(); // B6

  // ---- p6: S^-1 in-register Gauss-Jordan on wave 0 (no pivoting, SPD>=I).
  if (w == 0) {
    const int mr = l >> 1, half = l & 1;
    float s0[16];
    const float *gbase = sS + mr * 36 + half * 16;
    {
      f4 v0 = *(const f4 *)(gbase + 0), v1 = *(const f4 *)(gbase + 4);
      f4 v2 = *(const f4 *)(gbase + 8), v3 = *(const f4 *)(gbase + 12);
#pragma unroll
      for (int j = 0; j < 4; ++j) {
        s0[j] = v0[j]; s0[4 + j] = v1[j]; s0[8 + j] = v2[j]; s0[12 + j] = v3[j];
      }
    }
#pragma unroll
    for (int p = 0; p < 32; ++p) {
      const int ph = p >> 4, pi = p & 15;
      float prow[16];
#pragma unroll
      for (int j = 0; j < 16; ++j) prow[j] = __shfl(s0[j], 2 * p + half, 64);
      const float dpp = __shfl(s0[pi], 2 * p + ph, 64);
      const float d = 1.0f / dpp;
      const float fv = __shfl(s0[pi], (l & 62) + ph, 64);
      if (mr == p) {
#pragma unroll
        for (int j = 0; j < 16; ++j) s0[j] = prow[j] * d;
        if (half == ph) s0[pi] = d;
      } else {
        const float fd = fv * d;
#pragma unroll
        for (int j = 0; j < 16; ++j) s0[j] = fmaf(-fd, prow[j], s0[j]);
        if (half == ph) s0[pi] = -fd;
      }
    }
    float *wbase = sS + mr * 36 + half * 16;
    f4 w0 = {s0[0], s0[1], s0[2], s0[3]};
    f4 w1 = {s0[4], s0[5], s0[6], s0[7]};
    f4 w2 = {s0[8], s0[9], s0[10], s0[11]};
    f4 w3 = {s0[12], s0[13], s0[14], s0[15]};
    *(f4 *)(wbase + 0) = w0;
    *(f4 *)(wbase + 4) = w1;
    *(f4 *)(wbase + 8) = w2;
    *(f4 *)(wbase + 12) = w3;
  }
  __syncthreads(); // B7

  // ---- p7 (MFMA): K = PHt * S^-1 (A = PHt band-local; B row-read via
  //      S^-1 symmetry). Writes sK over dead T rows 32..63.
  {
    f32x4 acc[2] = {{0.f, 0.f, 0.f, 0.f}, {0.f, 0.f, 0.f, 0.f}};
    const int m = 16 * w + lr;
    const int k = h * 8;
    f4 a0 = *(const f4 *)(sPHt + m * 36 + k);
    f4 a1 = *(const f4 *)(sPHt + m * 36 + k + 4);
    b16x8 Ah, Al;
    split8v(a0, a1, Ah, Al);
#pragma unroll
    for (int t = 0; t < 2; ++t) {
      const int n = t * 16 + lr;
      f4 b0 = *(const f4 *)(sS + n * 36 + k);
      f4 b1 = *(const f4 *)(sS + n * 36 + k + 4);
      b16x8 Bh, Bl;
      split8v(b0, b1, Bh, Bl);
      acc[t] = MFMA(Ah, Bh, acc[t]);
      acc[t] = MFMA(Al, Bh, acc[t]);
      acc[t] = MFMA(Ah, Bl, acc[t]);
    }
    const int r0 = 16 * w + h * 4;
#pragma unroll
    for (int t = 0; t < 2; ++t)
#pragma unroll
      for (int j = 0; j < 4; ++j)
        sK[(r0 + j) * 36 + t * 16 + lr] = acc[t][j];
  }
  __syncthreads(); // B8

  // ---- p8: state_update (wave 0) + cov_update = cov_pred - K*PHt^T (MFMA)
  if (tid < 64) {
    float su = sy[tid];
#pragma unroll
    for (int ob = 0; ob < 32; ob += 4) {
      f4 kv = *(const f4 *)(sK + tid * 36 + ob);
      su += kv[0] * sresid[ob] + kv[1] * sresid[ob + 1] +
            kv[2] * sresid[ob + 2] + kv[3] * sresid[ob + 3];
    }
    out[b * 64 + tid] = su;
  }
  {
    const int m = 16 * w + lr;
    const int k = h * 8;
    f4 a0 = *(const f4 *)(sK + m * 36 + k);
    f4 a1 = *(const f4 *)(sK + m * 36 + k + 4);
    a0 = -a0;
    a1 = -a1;
    b16x8 Ah, Al;
    split8v(a0, a1, Ah, Al);
    const int r0 = 16 * w + h * 4;
    float *outc = out + CU_OFF + (size_t)b * 4096;
#pragma unroll
    for (int t = 0; t < 4; ++t) {
      const int n = t * 16 + lr;
      f4 b0 = *(const f4 *)(sPHt + n * 36 + k);
      f4 b1 = *(const f4 *)(sPHt + n * 36 + k + 4);
      b16x8 Bh, Bl;
      split8v(b0, b1, Bh, Bl);
      f32x4 acc;
#pragma unroll
      for (int j = 0; j < 4; ++j) acc[j] = sCov[(r0 + j) * 68 + n];
      acc = MFMA(Ah, Bh, acc);
      acc = MFMA(Al, Bh, acc);
      acc = MFMA(Ah, Bl, acc);
#pragma unroll
      for (int j = 0; j < 4; ++j) {
        const int rr = r0 + j;
        outc[rr * 64 + n] = acc[j];
        if (rr == n) out[CD_OFF + b * 64 + rr] = acc[j];
      }
    }
  }
}

extern "C" void kernel_launch(void *const *d_in, const int *in_sizes, int n_in,
                              void *d_out, int out_size, void *d_ws,
                              size_t ws_size, hipStream_t stream) {
  const float *obs = (const float *)d_in[0];
  const float *prev_state = (const float *)d_in[1];
  const float *prev_cov = (const float *)d_in[2];
  const float *coeffs = (const float *)d_in[3];
  const float *Hm = (const float *)d_in[4];
  const float *logQ = (const float *)d_in[5];
  const float *logR = (const float *)d_in[6];
  const int *tptr = (const int *)d_in[7];
  (void)in_sizes; (void)n_in; (void)out_size; (void)d_ws; (void)ws_size;
  kalman_fused<<<dim3(4096), dim3(256), 0, stream>>>(
      obs, prev_state, prev_cov, coeffs, Hm, logQ, logR, tptr, (float *)d_out);
}

// Round 7
// 115.850 us; speedup vs baseline: 8.8564x; 1.1105x over previous
//
#include <hip/hip_runtime.h>
#include <math.h>

// DifferentiableKalmanCell: B=4096, STATE=64, OBS=32, coeffs (64,64,11), t scalar.
// One block per batch; MFMA (bf16 split hi/lo) for all GEMM phases; Chebyshev by
// recurrence; S^-1 by single-wave register Gauss-Jordan.
// R7: LDS 43008 -> 38144 B => 4 blocks/CU.
//   - P/F splits: u16[64][64] XOR-swizzled (chunk ^ (row&7)), no pad.
//   - T, cov_pred: packed u32 (hi16|lo16) [64][64] swizzled; PHt, K: [64][32].
//     Packing is bit-identical to split-on-read (split moved to write time).
//   Layout: @0 Ph|Pl -> T -> PHt|K (16384) | @16384 Fh|Fl -> cov (16384)
//           @32768 S[32][36] f32 (ypart/tanh-scalar overlay pre-p5) (4608)
//           @37376 sy,sresid,sq,sr (768)  => total 38144.

typedef float f4 __attribute__((ext_vector_type(4)));
typedef float f32x4 __attribute__((ext_vector_type(4)));
typedef short b16x8 __attribute__((ext_vector_type(8)));
typedef short b16x4 __attribute__((ext_vector_type(4)));
typedef unsigned int u32;
typedef unsigned int u32x4 __attribute__((ext_vector_type(4)));
typedef unsigned short u16;

#define EPSC 1e-7f
#define MFMA(a, b, c) __builtin_amdgcn_mfma_f32_16x16x32_bf16(a, b, c, 0, 0, 0)
static constexpr size_t CU_OFF = 4096 * 64;
static constexpr size_t CD_OFF = CU_OFF + 4096ull * 4096;

__device__ __forceinline__ void split2(float x, short &h, short &l) {
  u32 u = __float_as_uint(x);
  h = (short)(u >> 16);
  float rem = x - __uint_as_float(u & 0xffff0000u);
  l = (short)(__float_as_uint(rem) >> 16);
}
__device__ __forceinline__ u32 packsplit(float x) {
  u32 u = __float_as_uint(x) & 0xffff0000u;
  float rem = x - __uint_as_float(u);
  return u | (__float_as_uint(rem) >> 16);
}
__device__ __forceinline__ float unpackf(u32 v) {
  return __uint_as_float(v & 0xffff0000u) + __uint_as_float(v << 16);
}
union U8 { u32x4 u; b16x8 s; };
__device__ __forceinline__ void unpack8(u32x4 q0, u32x4 q1, b16x8 &hi,
                                        b16x8 &lo) {
  U8 H, L;
  H.u[0] = __builtin_amdgcn_perm(q0[1], q0[0], 0x07060302u);
  H.u[1] = __builtin_amdgcn_perm(q0[3], q0[2], 0x07060302u);
  H.u[2] = __builtin_amdgcn_perm(q1[1], q1[0], 0x07060302u);
  H.u[3] = __builtin_amdgcn_perm(q1[3], q1[2], 0x07060302u);
  L.u[0] = __builtin_amdgcn_perm(q0[1], q0[0], 0x05040100u);
  L.u[1] = __builtin_amdgcn_perm(q0[3], q0[2], 0x05040100u);
  L.u[2] = __builtin_amdgcn_perm(q1[1], q1[0], 0x05040100u);
  L.u[3] = __builtin_amdgcn_perm(q1[3], q1[2], 0x05040100u);
  hi = H.s;
  lo = L.s;
}
__device__ __forceinline__ void split8v(f4 a, f4 b, b16x8 &hi, b16x8 &lo) {
#pragma unroll
  for (int j = 0; j < 4; ++j) {
    short hh, ll;
    split2(a[j], hh, ll); hi[j] = hh; lo[j] = ll;
    split2(b[j], hh, ll); hi[4 + j] = hh; lo[4 + j] = ll;
  }
}

__global__ __launch_bounds__(256, 4) void kalman_fused(
    const float *__restrict__ obs, const float *__restrict__ prev_state,
    const float *__restrict__ prev_cov, const float *__restrict__ coeffs,
    const float *__restrict__ Hm, const float *__restrict__ logQ,
    const float *__restrict__ logR, const int *__restrict__ tptr,
    float *__restrict__ out) {
  __shared__ __align__(16) unsigned char pool[38144];
  u16 *sPh = (u16 *)(pool);            // [64][64] swz
  u16 *sPl = (u16 *)(pool + 8192);
  u32 *sT = (u32 *)(pool);             // packed [64][64] swz, over P
  u32 *sPHt = (u32 *)(pool);           // packed [64][32] swz, over T rows 0..31
  u32 *sK = (u32 *)(pool + 8192);      // packed [64][32] swz, over T rows 32..63
  u16 *sFh = (u16 *)(pool + 16384);    // [64][64] swz
  u16 *sFl = (u16 *)(pool + 24576);
  u32 *sCov = (u32 *)(pool + 16384);   // packed [64][64] swz, over F
  float *sS = (float *)(pool + 32768); // f32 [32][36]
  float *ypart = (float *)(pool + 32768); // overlay (dead before p5)
  float *sTv = (float *)(pool + 33792);
  float *sSn = (float *)(pool + 34048);
  float *sDth = (float *)(pool + 34304);
  float *sy = (float *)(pool + 37376);
  float *sresid = (float *)(pool + 37632);
  float *sq = (float *)(pool + 37760);
  float *sr = (float *)(pool + 38016);

  const int tid = (int)threadIdx.x;
  const int b = (int)blockIdx.x;
  const int w = tid >> 6;
  const int l = tid & 63;
  const int lr = l & 15;
  const int h = l >> 4;

  // degree(t): D = degree+1 = 9 + int(1 + sin(2*pi*t/95)), D in 9..11
  const int tval = tptr[0];
  const float ang = 6.28318530717958647f * ((float)tval / 95.0f);
  const int D = 9 + (int)(1.0f + sinf(ang));

  // ---- p0: stage P (bf16 hi/lo split, swizzled), q/r, tanh-chain scalars
  {
    const float *Pg = prev_cov + (size_t)b * 4096;
#pragma unroll
    for (int e = 0; e < 4; ++e) {
      const int idx = tid + 256 * e;
      f4 v = *(const f4 *)(Pg + 4 * idx);
      const int r = idx >> 4, c = (idx & 15) * 4;
      const int x = (r & 7) << 3;
      b16x4 h4, l4;
#pragma unroll
      for (int j = 0; j < 4; ++j) {
        short hh, ll;
        split2(v[j], hh, ll);
        h4[j] = hh; l4[j] = ll;
      }
      *(b16x4 *)(sPh + r * 64 + (c ^ x)) = h4;
      *(b16x4 *)(sPl + r * 64 + (c ^ x)) = l4;
    }
    if (tid < 64) {
      sq[tid] = expf(logQ[tid]);
      const float xx = prev_state[b * 64 + tid];
      const float tr_ = tanhf(xx);
      const float tv = fminf(fmaxf(tr_, -1.0f + EPSC), 1.0f - EPSC);
      const float sn = sqrtf(fmaxf(1.0f - tv * tv, 0.0f));
      const float mask = (tr_ > -1.0f + EPSC && tr_ < 1.0f - EPSC) ? 1.0f : 0.0f;
      sTv[tid] = tv;
      sSn[tid] = sn;
      sDth[tid] = -(1.0f - tr_ * tr_) * mask / sn;
    } else if (tid < 96) {
      sr[tid - 64] = expf(logR[tid - 64]);
    }
  }
  __syncthreads(); // B0

  // ---- p1: y partials + Jacobian F (Chebyshev recurrence), F -> split swz
  {
    const int o = tid & 63, g = tid >> 6;
    float yacc = 0.f;
    float fr[16];
#pragma unroll
    for (int ii = 0; ii < 16; ++ii) {
      const int i = g * 16 + ii;
      const float tv = sTv[i], sn = sSn[i], dth = sDth[i];
      const float *cp = coeffs + (size_t)(i * 64 + o) * 11;
      f4 q0 = *(const f4 *)(cp);
      f4 q1 = *(const f4 *)(cp + 4);
      f4 q2 = *(const f4 *)(cp + 7); // elements 7..10 (in-bounds at tail)
      float cy[11];
#pragma unroll
      for (int j = 0; j < 4; ++j) { cy[j] = q0[j]; cy[4 + j] = q1[j]; }
      cy[8] = q2[1]; cy[9] = q2[2]; cy[10] = q2[3];
      if (D < 10) cy[9] = 0.f;
      if (D < 11) cy[10] = 0.f;
      float yac = fmaf(cy[1], tv, cy[0]);
      float wac = cy[1] * sn;
      float cm2 = 1.f, cm1 = tv, sm2 = 0.f, sm1 = sn;
      const float tv2 = 2.f * tv;
#pragma unroll
      for (int d = 2; d <= 10; ++d) {
        const float cc = fmaf(tv2, cm1, -cm2);
        const float ss = fmaf(tv2, sm1, -sm2);
        yac = fmaf(cy[d], cc, yac);
        wac = fmaf(cy[d] * (float)d, ss, wac);
        cm2 = cm1; cm1 = cc; sm2 = sm1; sm1 = ss;
      }
      yacc += yac;
      fr[ii] = -dth * wac;
    }
    b16x8 fh0, fh1, fl0, fl1;
#pragma unroll
    for (int j = 0; j < 8; ++j) {
      short hh, ll;
      split2(fr[j], hh, ll); fh0[j] = hh; fl0[j] = ll;
      split2(fr[8 + j], hh, ll); fh1[j] = hh; fl1[j] = ll;
    }
    const int x = (o & 7) << 3;
    *(b16x8 *)(sFh + o * 64 + ((g * 16) ^ x)) = fh0;
    *(b16x8 *)(sFh + o * 64 + ((g * 16 + 8) ^ x)) = fh1;
    *(b16x8 *)(sFl + o * 64 + ((g * 16) ^ x)) = fl0;
    *(b16x8 *)(sFl + o * 64 + ((g * 16 + 8) ^ x)) = fl1;
    ypart[g * 64 + o] = yacc;
  }
  __syncthreads(); // B1
  if (tid < 64)
    sy[tid] = ypart[tid] + ypart[64 + tid] + ypart[128 + tid] + ypart[192 + tid];
  __syncthreads(); // B2

  // residual (tid<32; overlaps p2 for the rest)
  if (tid < 32) {
    float racc = obs[b * 32 + tid];
    const float *Hr = Hm + tid * 64;
#pragma unroll
    for (int s = 0; s < 64; s += 4) {
      f4 hv = *(const f4 *)(Hr + s);
      racc -= hv[0] * sy[s] + hv[1] * sy[s + 1] + hv[2] * sy[s + 2] +
              hv[3] * sy[s + 3];
    }
    sresid[tid] = racc;
  }

  // ---- p2 (MFMA): T = F * P (P symmetric -> B-frag = row read)
  f32x4 accT[4] = {{0.f, 0.f, 0.f, 0.f}, {0.f, 0.f, 0.f, 0.f},
                   {0.f, 0.f, 0.f, 0.f}, {0.f, 0.f, 0.f, 0.f}};
  {
    const int m = 16 * w + lr;
    const int xA = (m & 7) << 3;
#pragma unroll
    for (int kc = 0; kc < 2; ++kc) {
      const int k = kc * 32 + h * 8;
      b16x8 Ah = *(const b16x8 *)(sFh + m * 64 + (k ^ xA));
      b16x8 Al = *(const b16x8 *)(sFl + m * 64 + (k ^ xA));
#pragma unroll
      for (int t = 0; t < 4; ++t) {
        const int n = t * 16 + lr;
        const int xB = (n & 7) << 3;
        b16x8 Bh = *(const b16x8 *)(sPh + n * 64 + (k ^ xB));
        b16x8 Bl = *(const b16x8 *)(sPl + n * 64 + (k ^ xB));
        accT[t] = MFMA(Ah, Bh, accT[t]);
        accT[t] = MFMA(Al, Bh, accT[t]);
        accT[t] = MFMA(Ah, Bl, accT[t]);
      }
    }
  }
  __syncthreads(); // B3: P reads drained; overwrite with packed T
  {
    const int r0 = 16 * w + h * 4;
#pragma unroll
    for (int t = 0; t < 4; ++t)
#pragma unroll
      for (int j = 0; j < 4; ++j) {
        const int rr = r0 + j, cc = t * 16 + lr;
        sT[rr * 64 + (cc ^ ((rr & 7) << 2))] = packsplit(accT[t][j]);
      }
  }

  // ---- p3 (MFMA): cov_pred = T * F^T + diag(q). A = T band-local.
  f32x4 accC[4] = {{0.f, 0.f, 0.f, 0.f}, {0.f, 0.f, 0.f, 0.f},
                   {0.f, 0.f, 0.f, 0.f}, {0.f, 0.f, 0.f, 0.f}};
  {
    const int m = 16 * w + lr;
    const int xA = (m & 7) << 2;
    const u32 *Tb = sT + m * 64;
#pragma unroll
    for (int kc = 0; kc < 2; ++kc) {
      const int k = kc * 32 + h * 8;
      u32x4 q0 = *(const u32x4 *)(Tb + (k ^ xA));
      u32x4 q1 = *(const u32x4 *)(Tb + ((k + 4) ^ xA));
      b16x8 Ah, Al;
      unpack8(q0, q1, Ah, Al);
#pragma unroll
      for (int t = 0; t < 4; ++t) {
        const int n = t * 16 + lr;
        const int xB = (n & 7) << 3;
        b16x8 Bh = *(const b16x8 *)(sFh + n * 64 + (k ^ xB));
        b16x8 Bl = *(const b16x8 *)(sFl + n * 64 + (k ^ xB));
        accC[t] = MFMA(Ah, Bh, accC[t]);
        accC[t] = MFMA(Al, Bh, accC[t]);
        accC[t] = MFMA(Ah, Bl, accC[t]);
      }
    }
  }
  __syncthreads(); // B4: F and T reads drained; overwrite F with packed cov
  {
    const int r0 = 16 * w + h * 4;
#pragma unroll
    for (int t = 0; t < 4; ++t)
#pragma unroll
      for (int j = 0; j < 4; ++j) {
        const int rr = r0 + j, cc = t * 16 + lr;
        float v = accC[t][j];
        if (rr == cc) v += sq[rr];
        sCov[rr * 64 + (cc ^ ((rr & 7) << 2))] = packsplit(v);
      }
  }

  // ---- p4 (MFMA): PHt = cov_pred * H^T (A = cov band-local; B = H global).
  //      Writes packed sPHt over dead T rows 0..31.
  {
    f32x4 acc[2] = {{0.f, 0.f, 0.f, 0.f}, {0.f, 0.f, 0.f, 0.f}};
    const int m = 16 * w + lr;
    const int xA = (m & 7) << 2;
    const u32 *Cb = sCov + m * 64;
#pragma unroll
    for (int kc = 0; kc < 2; ++kc) {
      const int k = kc * 32 + h * 8;
      u32x4 q0 = *(const u32x4 *)(Cb + (k ^ xA));
      u32x4 q1 = *(const u32x4 *)(Cb + ((k + 4) ^ xA));
      b16x8 Ah, Al;
      unpack8(q0, q1, Ah, Al);
#pragma unroll
      for (int t = 0; t < 2; ++t) {
        const int n = t * 16 + lr;
        const float *Hr = Hm + n * 64 + k;
        f4 b0 = *(const f4 *)(Hr);
        f4 b1 = *(const f4 *)(Hr + 4);
        b16x8 Bh, Bl;
        split8v(b0, b1, Bh, Bl);
        acc[t] = MFMA(Ah, Bh, acc[t]);
        acc[t] = MFMA(Al, Bh, acc[t]);
        acc[t] = MFMA(Ah, Bl, acc[t]);
      }
    }
    const int r0 = 16 * w + h * 4;
#pragma unroll
    for (int t = 0; t < 2; ++t)
#pragma unroll
      for (int j = 0; j < 4; ++j) {
        const int rr = r0 + j, cc = t * 16 + lr;
        sPHt[rr * 32 + (cc ^ ((rr & 7) << 2))] = packsplit(acc[t][j]);
      }
  }
  __syncthreads(); // B5

  // ---- p5 (MFMA): S = H * PHt + diag(r); wave w -> tile (w>>1, w&1)
  {
    const int tr = w >> 1, tc = w & 1;
    f32x4 acc = {0.f, 0.f, 0.f, 0.f};
    const int m = tr * 16 + lr;
    const int n = tc * 16 + lr;
#pragma unroll
    for (int kc = 0; kc < 2; ++kc) {
      const int k = kc * 32 + h * 8;
      const float *Hr = Hm + m * 64 + k;
      f4 a0 = *(const f4 *)(Hr);
      f4 a1 = *(const f4 *)(Hr + 4);
      b16x8 Ah, Al;
      split8v(a0, a1, Ah, Al);
      u32x4 q0, q1;
#pragma unroll
      for (int j = 0; j < 4; ++j)
        q0[j] = sPHt[(k + j) * 32 + (n ^ (j << 2))];
#pragma unroll
      for (int j = 0; j < 4; ++j)
        q1[j] = sPHt[(k + 4 + j) * 32 + (n ^ ((4 + j) << 2))];
      b16x8 Bh, Bl;
      unpack8(q0, q1, Bh, Bl);
      acc = MFMA(Ah, Bh, acc);
      acc = MFMA(Al, Bh, acc);
      acc = MFMA(Ah, Bl, acc);
    }
    const int r0 = tr * 16 + h * 4;
#pragma unroll
    for (int j = 0; j < 4; ++j) {
      const int rr = r0 + j, cc = tc * 16 + lr;
      float v = acc[j];
      if (rr == cc) v += sr[rr];
      sS[rr * 36 + cc] = v;
    }
  }
  __syncthreads(); // B6

  // ---- p6: S^-1 in-register Gauss-Jordan on wave 0 (no pivoting, SPD>=I).
  if (w == 0) {
    const int mr = l >> 1, half = l & 1;
    float s0[16];
    const float *gbase = sS + mr * 36 + half * 16;
    {
      f4 v0 = *(const f4 *)(gbase + 0), v1 = *(const f4 *)(gbase + 4);
      f4 v2 = *(const f4 *)(gbase + 8), v3 = *(const f4 *)(gbase + 12);
#pragma unroll
      for (int j = 0; j < 4; ++j) {
        s0[j] = v0[j]; s0[4 + j] = v1[j]; s0[8 + j] = v2[j]; s0[12 + j] = v3[j];
      }
    }
#pragma unroll
    for (int p = 0; p < 32; ++p) {
      const int ph = p >> 4, pi = p & 15;
      float prow[16];
#pragma unroll
      for (int j = 0; j < 16; ++j) prow[j] = __shfl(s0[j], 2 * p + half, 64);
      const float dpp = __shfl(s0[pi], 2 * p + ph, 64);
      const float d = 1.0f / dpp;
      const float fv = __shfl(s0[pi], (l & 62) + ph, 64);
      if (mr == p) {
#pragma unroll
        for (int j = 0; j < 16; ++j) s0[j] = prow[j] * d;
        if (half == ph) s0[pi] = d;
      } else {
        const float fd = fv * d;
#pragma unroll
        for (int j = 0; j < 16; ++j) s0[j] = fmaf(-fd, prow[j], s0[j]);
        if (half == ph) s0[pi] = -fd;
      }
    }
    float *wbase = sS + mr * 36 + half * 16;
    f4 w0 = {s0[0], s0[1], s0[2], s0[3]};
    f4 w1 = {s0[4], s0[5], s0[6], s0[7]};
    f4 w2 = {s0[8], s0[9], s0[10], s0[11]};
    f4 w3 = {s0[12], s0[13], s0[14], s0[15]};
    *(f4 *)(wbase + 0) = w0;
    *(f4 *)(wbase + 4) = w1;
    *(f4 *)(wbase + 8) = w2;
    *(f4 *)(wbase + 12) = w3;
  }
  __syncthreads(); // B7

  // ---- p7 (MFMA): K = PHt * S^-1 (B row-read via S^-1 symmetry).
  //      Writes packed sK over dead T rows 32..63.
  {
    f32x4 acc[2] = {{0.f, 0.f, 0.f, 0.f}, {0.f, 0.f, 0.f, 0.f}};
    const int m = 16 * w + lr;
    const int xA = (m & 7) << 2;
    const int k = h * 8;
    u32x4 q0 = *(const u32x4 *)(sPHt + m * 32 + (k ^ xA));
    u32x4 q1 = *(const u32x4 *)(sPHt + m * 32 + ((k + 4) ^ xA));
    b16x8 Ah, Al;
    unpack8(q0, q1, Ah, Al);
#pragma unroll
    for (int t = 0; t < 2; ++t) {
      const int n = t * 16 + lr;
      f4 b0 = *(const f4 *)(sS + n * 36 + k);
      f4 b1 = *(const f4 *)(sS + n * 36 + k + 4);
      b16x8 Bh, Bl;
      split8v(b0, b1, Bh, Bl);
      acc[t] = MFMA(Ah, Bh, acc[t]);
      acc[t] = MFMA(Al, Bh, acc[t]);
      acc[t] = MFMA(Ah, Bl, acc[t]);
    }
    const int r0 = 16 * w + h * 4;
#pragma unroll
    for (int t = 0; t < 2; ++t)
#pragma unroll
      for (int j = 0; j < 4; ++j) {
        const int rr = r0 + j, cc = t * 16 + lr;
        sK[rr * 32 + (cc ^ ((rr & 7) << 2))] = packsplit(acc[t][j]);
      }
  }
  __syncthreads(); // B8

  // ---- p8: state_update (wave 0) + cov_update = cov_pred - K*PHt^T (MFMA)
  if (tid < 64) {
    float su = sy[tid];
    const int x = (tid & 7) << 2;
    const u32 *Kb = sK + tid * 32;
#pragma unroll
    for (int c0 = 0; c0 < 32; c0 += 4) {
      u32x4 q = *(const u32x4 *)(Kb + (c0 ^ x));
#pragma unroll
      for (int j = 0; j < 4; ++j)
        su = fmaf(unpackf(q[j]), sresid[c0 + j], su);
    }
    out[b * 64 + tid] = su;
  }
  {
    const int m = 16 * w + lr;
    const int xA = (m & 7) << 2;
    const int k = h * 8;
    u32x4 q0 = *(const u32x4 *)(sK + m * 32 + (k ^ xA));
    u32x4 q1 = *(const u32x4 *)(sK + m * 32 + ((k + 4) ^ xA));
#pragma unroll
    for (int j = 0; j < 4; ++j) { // negate both halves: -K
      q0[j] ^= 0x80008000u;
      q1[j] ^= 0x80008000u;
    }
    b16x8 Ah, Al;
    unpack8(q0, q1, Ah, Al);
    const int r0 = 16 * w + h * 4;
    float *outc = out + CU_OFF + (size_t)b * 4096;
#pragma unroll
    for (int t = 0; t < 4; ++t) {
      const int n = t * 16 + lr;
      const int xB = (n & 7) << 2;
      u32x4 p0 = *(const u32x4 *)(sPHt + n * 32 + (k ^ xB));
      u32x4 p1 = *(const u32x4 *)(sPHt + n * 32 + ((k + 4) ^ xB));
      b16x8 Bh, Bl;
      unpack8(p0, p1, Bh, Bl);
      f32x4 acc;
#pragma unroll
      for (int j = 0; j < 4; ++j) {
        const int rr = r0 + j;
        acc[j] = unpackf(sCov[rr * 64 + (n ^ ((rr & 7) << 2))]);
      }
      acc = MFMA(Ah, Bh, acc);
      acc = MFMA(Al, Bh, acc);
      acc = MFMA(Ah, Bl, acc);
#pragma unroll
      for (int j = 0; j < 4; ++j) {
        const int rr = r0 + j;
        outc[rr * 64 + n] = acc[j];
        if (rr == n) out[CD_OFF + b * 64 + rr] = acc[j];
      }
    }
  }
}

extern "C" void kernel_launch(void *const *d_in, const int *in_sizes, int n_in,
                              void *d_out, int out_size, void *d_ws,
                              size_t ws_size, hipStream_t stream) {
  const float *obs = (const float *)d_in[0];
  const float *prev_state = (const float *)d_in[1];
  const float *prev_cov = (const float *)d_in[2];
  const float *coeffs = (const float *)d_in[3];
  const float *Hm = (const float *)d_in[4];
  const float *logQ = (const float *)d_in[5];
  const float *logR = (const float *)d_in[6];
  const int *tptr = (const int *)d_in[7];
  (void)in_sizes; (void)n_in; (void)out_size; (void)d_ws; (void)ws_size;
  kalman_fused<<<dim3(4096), dim3(256), 0, stream>>>(
      obs, prev_state, prev_cov, coeffs, Hm, logQ, logR, tptr, (float *)d_out);
}